// Round 6
// baseline (2122.848 us; speedup 1.0000x reference)
//
#include <hip/hip_runtime.h>
#include <math.h>

#define NN 100000
#define NE 1200000
#define EMBD 100
#define HD 64
#define BT 4096
#define SCAN_B 98  // 98 * 1024 >= NN

typedef __attribute__((ext_vector_type(8))) short short8;  // 8 bf16 (4 VGPRs)
typedef __attribute__((ext_vector_type(4))) float f32x4;   // MFMA C/D

__device__ __forceinline__ float4 f4zero() { return make_float4(0.f, 0.f, 0.f, 0.f); }
__device__ __forceinline__ float sig1(float x) { return 1.f / (1.f + __expf(-x)); }
__device__ __forceinline__ float tanh1(float x) {
    x = fminf(fmaxf(x, -15.f), 15.f);
    float e = __expf(2.f * x);
    return (e - 1.f) / (e + 1.f);
}
// f32 -> bf16 (round-to-nearest-even), and bf16 -> f32 unpack helpers
__device__ __forceinline__ unsigned short f2b(float f) {
    unsigned u = __float_as_uint(f);
    u += 0x7fffu + ((u >> 16) & 1u);
    return (unsigned short)(u >> 16);
}
__device__ __forceinline__ float blo(unsigned u) { return __uint_as_float(u << 16); }
__device__ __forceinline__ float bhi(unsigned u) { return __uint_as_float(u & 0xffff0000u); }
__device__ __forceinline__ unsigned packb(float lo, float hi) {
    return (unsigned)f2b(lo) | ((unsigned)f2b(hi) << 16);
}

// ---- precompute Wf[l] = Wm[l] @ Wih[l] (64x192), bf[l] = bm[l] @ Wih[l] (192) ----
__global__ __launch_bounds__(256) void fusew_kernel(
    const float* __restrict__ Wm0, const float* __restrict__ Wih0, const float* __restrict__ bm0,
    const float* __restrict__ Wm1, const float* __restrict__ Wih1, const float* __restrict__ bm1,
    float* __restrict__ Wf, float* __restrict__ bf) {
    extern __shared__ float lds[];
    float* wm_s = lds;          // 4096
    float* wih_s = lds + 4096;  // 12288
    const int l = blockIdx.x >> 3, slice = blockIdx.x & 7;
    const float* Wm = l ? Wm1 : Wm0;
    const float* Wih = l ? Wih1 : Wih0;
    const float* bm = l ? bm1 : bm0;
    for (int i = threadIdx.x; i < 4096; i += 256) wm_s[i] = Wm[i];
    for (int i = threadIdx.x; i < 12288; i += 256) wih_s[i] = Wih[i];
    __syncthreads();
    float* Wfl = Wf + l * 12288;
    float* bfl = bf + l * 192;
    const int o0 = slice * 1536;
    for (int o = o0 + threadIdx.x; o < o0 + 1536; o += 256) {
        int r = o / 192, c = o % 192;
        float s = 0.f;
        for (int k = 0; k < 64; ++k) s = fmaf(wm_s[r * 64 + k], wih_s[k * 192 + c], s);
        Wfl[o] = s;
    }
    const int c0 = slice * 24;
    for (int c = c0 + threadIdx.x; c < c0 + 24; c += 256) {
        float s = 0.f;
        for (int k = 0; k < 64; ++k) s = fmaf(bm[k], wih_s[k * 192 + c], s);
        bfl[c] = s;
    }
}

// ---- pack W' (128x256) into MFMA B-fragment order, bf16 (layout verified in R5) ----
__global__ __launch_bounds__(64) void wpack_kernel(
    const float* __restrict__ Wf, const float* __restrict__ Whh0, const float* __restrict__ Whh1,
    unsigned short* __restrict__ Wpk) {
    const int b = blockIdx.x;  // 0..127
    const int l = b >> 6, frag = b & 63;
    const int nt = frag >> 2, kk = frag & 3;
    const int lane = threadIdx.x;
    const int n = nt * 16 + (lane & 15);
    const int g = n >> 6, j = n & 63;
    const int k0 = kk * 32 + (lane >> 4) * 8;
    const float* wf = Wf + l * 12288;
    const float* whh = l ? Whh1 : Whh0;
    unsigned short o[8];
#pragma unroll
    for (int jj = 0; jj < 8; ++jj) {
        const int k = k0 + jj;
        float v = 0.f;
        if (k < 64) {
            if (g == 0) v = wf[k * 192 + j];
            else if (g == 1) v = wf[k * 192 + 64 + j];
            else if (g == 2) v = wf[k * 192 + 128 + j];
        } else {
            const int k2 = k - 64;
            if (g == 0) v = whh[k2 * 192 + j];
            else if (g == 1) v = whh[k2 * 192 + 64 + j];
            else if (g == 3) v = whh[k2 * 192 + 128 + j];
        }
        o[jj] = f2b(v);
    }
    *(uint4*)(Wpk + ((size_t)(l * 64 + frag) * 64 + lane) * 8) = *(const uint4*)o;
}

// ---- h[n] = emb_table[ind[n]] @ Wp + bp ; also bf16 mirror hb ----
__global__ __launch_bounds__(256) void embed_kernel(
    const int* __restrict__ ind, const float* __restrict__ emb,
    const float* __restrict__ Wp, const float* __restrict__ bp,
    float* __restrict__ h, unsigned short* __restrict__ hb) {
    __shared__ float et[4][EMBD][4];  // [wave][k][node]
    const int w = threadIdx.x >> 6;
    const int l = threadIdx.x & 63;
    const int nodeBase = blockIdx.x * 16 + w * 4;
    for (int f = l; f < 100; f += 64) {
        const int n = f / 25, c = f % 25;
        const int idx = ind[nodeBase + n];
        const float4 v = *(const float4*)(emb + (size_t)idx * EMBD + c * 4);
        et[w][c * 4 + 0][n] = v.x;
        et[w][c * 4 + 1][n] = v.y;
        et[w][c * 4 + 2][n] = v.z;
        et[w][c * 4 + 3][n] = v.w;
    }
    __syncthreads();
    float acc0 = bp[l], acc1 = acc0, acc2 = acc0, acc3 = acc0;
#pragma unroll 5
    for (int k = 0; k < EMBD; ++k) {
        const float wv = Wp[k * 64 + l];
        const float4 ev = *(const float4*)&et[w][k][0];
        acc0 = fmaf(ev.x, wv, acc0);
        acc1 = fmaf(ev.y, wv, acc1);
        acc2 = fmaf(ev.z, wv, acc2);
        acc3 = fmaf(ev.w, wv, acc3);
    }
    h[(nodeBase + 0) * 64 + l] = acc0;
    h[(nodeBase + 1) * 64 + l] = acc1;
    h[(nodeBase + 2) * 64 + l] = acc2;
    h[(nodeBase + 3) * 64 + l] = acc3;
    hb[(nodeBase + 0) * 64 + l] = f2b(acc0);
    hb[(nodeBase + 1) * 64 + l] = f2b(acc1);
    hb[(nodeBase + 2) * 64 + l] = f2b(acc2);
    hb[(nodeBase + 3) * 64 + l] = f2b(acc3);
}

// ---- CSR build: histogram of in-degree into rowptr (pre-zeroed) ----
__global__ __launch_bounds__(256) void hist_kernel(const int* __restrict__ adj, int* __restrict__ rowptr) {
    const int e = blockIdx.x * 256 + threadIdx.x;
    if (e < NE) atomicAdd(&rowptr[adj[2 * e + 1]], 1);
}

// ---- hierarchical exclusive scan over rowptr ----
__global__ __launch_bounds__(256) void scan1_kernel(const int* __restrict__ rowptr, int* __restrict__ bsum) {
    __shared__ int red[256];
    const int t = threadIdx.x, b = blockIdx.x;
    const int base = b * 1024;
    int s = 0;
    for (int i = t; i < 1024; i += 256) {
        const int idx = base + i;
        s += (idx < NN) ? rowptr[idx] : 0;
    }
    red[t] = s;
    __syncthreads();
    for (int off = 128; off > 0; off >>= 1) {
        if (t < off) red[t] += red[t + off];
        __syncthreads();
    }
    if (t == 0) bsum[b] = red[0];
}

__global__ __launch_bounds__(128) void scan2_kernel(int* __restrict__ bsum) {
    __shared__ int s[128];
    const int t = threadIdx.x;
    const int v = (t < SCAN_B) ? bsum[t] : 0;
    s[t] = v;
    __syncthreads();
    for (int off = 1; off < 128; off <<= 1) {
        const int x = (t >= off) ? s[t - off] : 0;
        __syncthreads();
        s[t] += x;
        __syncthreads();
    }
    if (t < SCAN_B) bsum[t] = s[t] - v;  // exclusive
}

__global__ __launch_bounds__(256) void scan3_kernel(int* __restrict__ rowptr, const int* __restrict__ bsum,
                                                    float* __restrict__ deg) {
    __shared__ int red[256];
    const int t = threadIdx.x, b = blockIdx.x;
    const int i0 = b * 1024 + t * 4;
    int v[4];
#pragma unroll
    for (int j = 0; j < 4; ++j) v[j] = (i0 + j < NN) ? rowptr[i0 + j] : 0;
    const int ts = v[0] + v[1] + v[2] + v[3];
    red[t] = ts;
    __syncthreads();
    for (int off = 1; off < 256; off <<= 1) {
        const int x = (t >= off) ? red[t - off] : 0;
        __syncthreads();
        red[t] += x;
        __syncthreads();
    }
    int pre = bsum[b] + red[t] - ts;
#pragma unroll
    for (int j = 0; j < 4; ++j) {
        if (i0 + j < NN) {
            rowptr[i0 + j] = pre;
            deg[i0 + j] = (float)v[j];
            pre += v[j];
        }
    }
}

// ---- CSR build: fill. Uses rowptr as cursor; afterwards rowptr[n] == end offset of node n ----
__global__ __launch_bounds__(256) void fill_kernel(
    const int* __restrict__ adj, int* __restrict__ rowptr, int* __restrict__ csr) {
    const int e = blockIdx.x * 256 + threadIdx.x;
    if (e < NE) {
        const int2 st = ((const int2*)adj)[e];
        const int pos = atomicAdd(&rowptr[st.y], 1);
        csr[pos] = st.x;
    }
}

// ---- FUSED agg + MFMA GRU ----
// One wave per 16-node tile. Lane (m=lane&15, quad) accumulates the agg A-fragment
// directly in registers while gathering hb_old[src] rows over node m's CSR list
// (A[m][k=kk*32+quad*8+j] = 16 contiguous bytes). Then one 16x128 @ 128x256 MFMA
// GEMM against LDS-staged W', gate math, write h (fp32, tile-local) + hb_new.
__global__ __launch_bounds__(256) void gru_fused_kernel(
    float* __restrict__ h, const unsigned short* __restrict__ hb_old,
    unsigned short* __restrict__ hb_new,
    const int* __restrict__ rowptr, const int* __restrict__ csr, const float* __restrict__ deg,
    const unsigned short* __restrict__ Wpk, const float* __restrict__ bfv,
    const float* __restrict__ bih, const float* __restrict__ bhh) {
    extern __shared__ unsigned short ldsW[];  // 64 frags x 64 lanes x 8 bf16 = 64 KB
    {
        const uint4* src = (const uint4*)Wpk;
        uint4* dst = (uint4*)ldsW;
        for (int i = threadIdx.x; i < 4096; i += 256) dst[i] = src[i];
    }
    __syncthreads();
    const int wv = (blockIdx.x * 256 + threadIdx.x) >> 6;  // global wave id == tile
    if (wv >= NN / 16) return;
    const int lane = threadIdx.x & 63;
    const int m = lane & 15, quad = lane >> 4, q8 = quad * 8;
    const int tbase = wv * 16;
    const int node = tbase + m;
    const int start = node ? rowptr[node - 1] : 0;
    const int end = rowptr[node];
    // ---- register-resident gather of the agg A-fragment ----
    float ga[16];
#pragma unroll
    for (int i = 0; i < 16; ++i) ga[i] = 0.f;
    int e = start;
    for (; e + 1 < end; e += 2) {
        const int s0 = csr[e], s1 = csr[e + 1];
        const uint4 u0 = *(const uint4*)(hb_old + s0 * 64 + q8);
        const uint4 v0 = *(const uint4*)(hb_old + s0 * 64 + 32 + q8);
        const uint4 u1 = *(const uint4*)(hb_old + s1 * 64 + q8);
        const uint4 v1 = *(const uint4*)(hb_old + s1 * 64 + 32 + q8);
        ga[0] += blo(u0.x); ga[1] += bhi(u0.x); ga[2] += blo(u0.y); ga[3] += bhi(u0.y);
        ga[4] += blo(u0.z); ga[5] += bhi(u0.z); ga[6] += blo(u0.w); ga[7] += bhi(u0.w);
        ga[8] += blo(v0.x); ga[9] += bhi(v0.x); ga[10] += blo(v0.y); ga[11] += bhi(v0.y);
        ga[12] += blo(v0.z); ga[13] += bhi(v0.z); ga[14] += blo(v0.w); ga[15] += bhi(v0.w);
        ga[0] += blo(u1.x); ga[1] += bhi(u1.x); ga[2] += blo(u1.y); ga[3] += bhi(u1.y);
        ga[4] += blo(u1.z); ga[5] += bhi(u1.z); ga[6] += blo(u1.w); ga[7] += bhi(u1.w);
        ga[8] += blo(v1.x); ga[9] += bhi(v1.x); ga[10] += blo(v1.y); ga[11] += bhi(v1.y);
        ga[12] += blo(v1.z); ga[13] += bhi(v1.z); ga[14] += blo(v1.w); ga[15] += bhi(v1.w);
    }
    if (e < end) {
        const int s0 = csr[e];
        const uint4 u0 = *(const uint4*)(hb_old + s0 * 64 + q8);
        const uint4 v0 = *(const uint4*)(hb_old + s0 * 64 + 32 + q8);
        ga[0] += blo(u0.x); ga[1] += bhi(u0.x); ga[2] += blo(u0.y); ga[3] += bhi(u0.y);
        ga[4] += blo(u0.z); ga[5] += bhi(u0.z); ga[6] += blo(u0.w); ga[7] += bhi(u0.w);
        ga[8] += blo(v0.x); ga[9] += bhi(v0.x); ga[10] += blo(v0.y); ga[11] += bhi(v0.y);
        ga[12] += blo(v0.z); ga[13] += bhi(v0.z); ga[14] += blo(v0.w); ga[15] += bhi(v0.w);
    }
    // ---- build A fragments ----
    short8 a[4];
#pragma unroll
    for (int j = 0; j < 8; ++j) a[0][j] = (short)f2b(ga[j]);
#pragma unroll
    for (int j = 0; j < 8; ++j) a[1][j] = (short)f2b(ga[8 + j]);
    a[2] = *(const short8*)(hb_old + node * 64 + q8);
    a[3] = *(const short8*)(hb_old + node * 64 + 32 + q8);
    // ---- MFMA ----
    const short8* ldsW8 = (const short8*)ldsW;
    f32x4 acc[16];
#pragma unroll
    for (int i = 0; i < 16; ++i) acc[i] = (f32x4){0.f, 0.f, 0.f, 0.f};
#pragma unroll
    for (int nt = 0; nt < 16; ++nt) {
#pragma unroll
        for (int kk = 0; kk < 4; ++kk) {
            acc[nt] = __builtin_amdgcn_mfma_f32_16x16x32_bf16(a[kk], ldsW8[(nt * 4 + kk) * 64 + lane],
                                                              acc[nt], 0, 0, 0);
        }
    }
    // ---- epilogue: gates + state update (C/D: row=quad*4+reg, col=c4*16+m) ----
#pragma unroll
    for (int reg = 0; reg < 4; ++reg) {
        const int n2 = tbase + quad * 4 + reg;
        const float dg = deg[n2];
#pragma unroll
        for (int c4 = 0; c4 < 4; ++c4) {
            const int col = c4 * 16 + m;
            const float rv = sig1(acc[c4][reg] + bih[col] + bhh[col] + dg * bfv[col]);
            const float zv = sig1(acc[4 + c4][reg] + bih[64 + col] + bhh[64 + col] + dg * bfv[64 + col]);
            const float gi = acc[8 + c4][reg] + bih[128 + col] + dg * bfv[128 + col];
            const float gh = acc[12 + c4][reg] + bhh[128 + col];
            const float nv = tanh1(fmaf(rv, gh, gi));
            const float hold = h[n2 * 64 + col];
            const float hn = (1.f - zv) * nv + zv * hold;
            h[n2 * 64 + col] = hn;
            hb_new[n2 * 64 + col] = f2b(hn);
        }
    }
}

// ---- X[b, g*64 + j] = h[prop[b]][j] ----
__global__ __launch_bounds__(256) void gather_kernel(
    const int* __restrict__ prop, const float* __restrict__ h, float* __restrict__ X, int g) {
    const int b = blockIdx.x * 4 + (threadIdx.x >> 6);
    const int j = threadIdx.x & 63;
    X[b * 128 + g * 64 + j] = h[prop[b] * 64 + j];
}

// ---- hidden = relu(X@W1+b1); z = hidden@W2+b2; out[b]=sigmoid(z); zbuf[b]=z ----
__global__ __launch_bounds__(256) void mlp_kernel(
    const float* __restrict__ X, const float* __restrict__ W1, const float* __restrict__ b1,
    const float* __restrict__ W2, const float* __restrict__ b2,
    float* __restrict__ out, float* __restrict__ zbuf) {
    const int b = blockIdx.x * 4 + (threadIdx.x >> 6);
    const int j = threadIdx.x & 63;
    const float* x = X + b * 128;
    float acc = b1[j];
#pragma unroll 4
    for (int k = 0; k < 128; ++k) acc = fmaf(x[k], W1[k * 64 + j], acc);
    float v = fmaxf(acc, 0.f) * W2[j];
#pragma unroll
    for (int off = 32; off > 0; off >>= 1) v += __shfl_down(v, off);
    if (j == 0) {
        const float z = v + b2[0];
        out[b] = 1.f / (1.f + expf(-z));
        zbuf[b] = z;
    }
}

// ---- loss = -mean(y*logsig(z) + (1-y)*logsig(-z)) -> out[BT] ----
__global__ __launch_bounds__(256) void loss_kernel(
    const float* __restrict__ zbuf, const int* __restrict__ labels, float* __restrict__ out) {
    __shared__ float red[256];
    const int t = threadIdx.x;
    float s = 0.f;
    for (int i = t; i < BT; i += 256) {
        const float z = zbuf[i];
        const float y = (float)labels[i];
        const float lsp = (z >= 0.f) ? -log1pf(expf(-z)) : (z - log1pf(expf(z)));
        const float lsn = lsp - z;
        s += y * lsp + (1.f - y) * lsn;
    }
    red[t] = s;
    __syncthreads();
    for (int off = 128; off > 0; off >>= 1) {
        if (t < off) red[t] += red[t + off];
        __syncthreads();
    }
    if (t == 0) out[BT] = -red[0] / (float)BT;
}

extern "C" void kernel_launch(void* const* d_in, const int* in_sizes, int n_in,
                              void* d_out, int out_size, void* d_ws, size_t ws_size,
                              hipStream_t stream) {
    char* ws = (char*)d_ws;
    float* h = (float*)(ws);                                  // 25,600,000 B
    unsigned short* hb0 = (unsigned short*)(ws + 25600000);   // 12,800,000 B
    unsigned short* hb1 = (unsigned short*)(ws + 38400000);   // 12,800,000 B
    float* deg = (float*)(ws + 51200000);                     // 400,000 B
    float* Wf = (float*)(ws + 51600000);                      // 98,304 B
    float* bf = (float*)(ws + 51698304);                      // 1,536 B
    int* rowptr = (int*)(ws + 51699840);                      // 400,000 B
    int* csr = (int*)(ws + 52099840);                         // 4,800,000 B
    int* bsum = (int*)(ws + 56899840);                        // 512 B
    float* X = (float*)(ws + 56900352);                       // 2,097,152 B
    float* zbuf = (float*)(ws + 58997504);                    // 16,384 B
    unsigned short* Wpk = (unsigned short*)(ws + 59013888);   // 131,072 B
    float* out = (float*)d_out;

    const float* emb_table = (const float*)d_in[7];
    const float* Wp = (const float*)d_in[8];
    const float* bp = (const float*)d_in[9];

    fusew_kernel<<<16, 256, 65536, stream>>>(
        (const float*)d_in[10], (const float*)d_in[12], (const float*)d_in[11],
        (const float*)d_in[16], (const float*)d_in[18], (const float*)d_in[17], Wf, bf);
    wpack_kernel<<<128, 64, 0, stream>>>(Wf, (const float*)d_in[13], (const float*)d_in[19], Wpk);

    const int GRU_BLOCKS = (NN / 16 + 3) / 4;  // 1563: one wave per 16-node tile

    for (int g = 0; g < 2; ++g) {
        const int* adjg = (const int*)d_in[2 + g];
        // CSR build for this graph
        hipMemsetAsync(rowptr, 0, (size_t)NN * 4, stream);
        hist_kernel<<<(NE + 255) / 256, 256, 0, stream>>>(adjg, rowptr);
        scan1_kernel<<<SCAN_B, 256, 0, stream>>>(rowptr, bsum);
        scan2_kernel<<<1, 128, 0, stream>>>(bsum);
        scan3_kernel<<<SCAN_B, 256, 0, stream>>>(rowptr, bsum, deg);
        fill_kernel<<<(NE + 255) / 256, 256, 0, stream>>>(adjg, rowptr, csr);

        embed_kernel<<<NN / 16, 256, 0, stream>>>((const int*)d_in[g], emb_table, Wp, bp, h, hb0);
        unsigned short* cur = hb0;
        unsigned short* nxt = hb1;
        for (int l = 0; l < 2; ++l) {
            const float* bih = (const float*)d_in[14 + 6 * l];
            const float* bhh = (const float*)d_in[15 + 6 * l];
            for (int ts = 0; ts < 3; ++ts) {
                gru_fused_kernel<<<GRU_BLOCKS, 256, 65536, stream>>>(
                    h, cur, nxt, rowptr, csr, deg, Wpk + l * 32768, bf + l * 192, bih, bhh);
                unsigned short* tmp = cur; cur = nxt; nxt = tmp;
            }
        }
        gather_kernel<<<BT / 4, 256, 0, stream>>>((const int*)d_in[4 + g], h, X, g);
    }
    mlp_kernel<<<BT / 4, 256, 0, stream>>>(X, (const float*)d_in[22], (const float*)d_in[23],
                                           (const float*)d_in[24], (const float*)d_in[25], out, zbuf);
    loss_kernel<<<1, 256, 0, stream>>>(zbuf, (const int*)d_in[6], out);
}

// Round 7
// 2106.999 us; speedup vs baseline: 1.0075x; 1.0075x over previous
//
#include <hip/hip_runtime.h>
#include <math.h>

#define NN 100000
#define NE 1200000
#define EMBD 100
#define HD 64
#define BT 4096
#define SCAN_B 98  // 98 * 1024 >= NN

typedef __attribute__((ext_vector_type(8))) short short8;  // 8 bf16 (4 VGPRs)
typedef __attribute__((ext_vector_type(4))) float f32x4;   // MFMA C/D

__device__ __forceinline__ float4 f4zero() { return make_float4(0.f, 0.f, 0.f, 0.f); }
__device__ __forceinline__ float sig1(float x) { return 1.f / (1.f + __expf(-x)); }
__device__ __forceinline__ float tanh1(float x) {
    x = fminf(fmaxf(x, -15.f), 15.f);
    float e = __expf(2.f * x);
    return (e - 1.f) / (e + 1.f);
}
// f32 -> bf16 (round-to-nearest-even), and bf16 -> f32 unpack helpers
__device__ __forceinline__ unsigned short f2b(float f) {
    unsigned u = __float_as_uint(f);
    u += 0x7fffu + ((u >> 16) & 1u);
    return (unsigned short)(u >> 16);
}
__device__ __forceinline__ float blo(unsigned u) { return __uint_as_float(u << 16); }
__device__ __forceinline__ float bhi(unsigned u) { return __uint_as_float(u & 0xffff0000u); }
__device__ __forceinline__ unsigned packb(float lo, float hi) {
    return (unsigned)f2b(lo) | ((unsigned)f2b(hi) << 16);
}

// ---- precompute Wf[l] = Wm[l] @ Wih[l] (64x192), bf[l] = bm[l] @ Wih[l] (192) ----
__global__ __launch_bounds__(256) void fusew_kernel(
    const float* __restrict__ Wm0, const float* __restrict__ Wih0, const float* __restrict__ bm0,
    const float* __restrict__ Wm1, const float* __restrict__ Wih1, const float* __restrict__ bm1,
    float* __restrict__ Wf, float* __restrict__ bf) {
    extern __shared__ float lds[];
    float* wm_s = lds;          // 4096
    float* wih_s = lds + 4096;  // 12288
    const int l = blockIdx.x >> 3, slice = blockIdx.x & 7;
    const float* Wm = l ? Wm1 : Wm0;
    const float* Wih = l ? Wih1 : Wih0;
    const float* bm = l ? bm1 : bm0;
    for (int i = threadIdx.x; i < 4096; i += 256) wm_s[i] = Wm[i];
    for (int i = threadIdx.x; i < 12288; i += 256) wih_s[i] = Wih[i];
    __syncthreads();
    float* Wfl = Wf + l * 12288;
    float* bfl = bf + l * 192;
    const int o0 = slice * 1536;
    for (int o = o0 + threadIdx.x; o < o0 + 1536; o += 256) {
        int r = o / 192, c = o % 192;
        float s = 0.f;
        for (int k = 0; k < 64; ++k) s = fmaf(wm_s[r * 64 + k], wih_s[k * 192 + c], s);
        Wfl[o] = s;
    }
    const int c0 = slice * 24;
    for (int c = c0 + threadIdx.x; c < c0 + 24; c += 256) {
        float s = 0.f;
        for (int k = 0; k < 64; ++k) s = fmaf(bm[k], wih_s[k * 192 + c], s);
        bfl[c] = s;
    }
}

// ---- pack W' (128x256) into MFMA B-fragment order, bf16 (layout verified in R5) ----
__global__ __launch_bounds__(64) void wpack_kernel(
    const float* __restrict__ Wf, const float* __restrict__ Whh0, const float* __restrict__ Whh1,
    unsigned short* __restrict__ Wpk) {
    const int b = blockIdx.x;  // 0..127
    const int l = b >> 6, frag = b & 63;
    const int nt = frag >> 2, kk = frag & 3;
    const int lane = threadIdx.x;
    const int n = nt * 16 + (lane & 15);
    const int g = n >> 6, j = n & 63;
    const int k0 = kk * 32 + (lane >> 4) * 8;
    const float* wf = Wf + l * 12288;
    const float* whh = l ? Whh1 : Whh0;
    unsigned short o[8];
#pragma unroll
    for (int jj = 0; jj < 8; ++jj) {
        const int k = k0 + jj;
        float v = 0.f;
        if (k < 64) {
            if (g == 0) v = wf[k * 192 + j];
            else if (g == 1) v = wf[k * 192 + 64 + j];
            else if (g == 2) v = wf[k * 192 + 128 + j];
        } else {
            const int k2 = k - 64;
            if (g == 0) v = whh[k2 * 192 + j];
            else if (g == 1) v = whh[k2 * 192 + 64 + j];
            else if (g == 3) v = whh[k2 * 192 + 128 + j];
        }
        o[jj] = f2b(v);
    }
    *(uint4*)(Wpk + ((size_t)(l * 64 + frag) * 64 + lane) * 8) = *(const uint4*)o;
}

// ---- h[n] = emb_table[ind[n]] @ Wp + bp ; also bf16 mirror hb ----
__global__ __launch_bounds__(256) void embed_kernel(
    const int* __restrict__ ind, const float* __restrict__ emb,
    const float* __restrict__ Wp, const float* __restrict__ bp,
    float* __restrict__ h, unsigned short* __restrict__ hb) {
    __shared__ float et[4][EMBD][4];  // [wave][k][node]
    const int w = threadIdx.x >> 6;
    const int l = threadIdx.x & 63;
    const int nodeBase = blockIdx.x * 16 + w * 4;
    for (int f = l; f < 100; f += 64) {
        const int n = f / 25, c = f % 25;
        const int idx = ind[nodeBase + n];
        const float4 v = *(const float4*)(emb + (size_t)idx * EMBD + c * 4);
        et[w][c * 4 + 0][n] = v.x;
        et[w][c * 4 + 1][n] = v.y;
        et[w][c * 4 + 2][n] = v.z;
        et[w][c * 4 + 3][n] = v.w;
    }
    __syncthreads();
    float acc0 = bp[l], acc1 = acc0, acc2 = acc0, acc3 = acc0;
#pragma unroll 5
    for (int k = 0; k < EMBD; ++k) {
        const float wv = Wp[k * 64 + l];
        const float4 ev = *(const float4*)&et[w][k][0];
        acc0 = fmaf(ev.x, wv, acc0);
        acc1 = fmaf(ev.y, wv, acc1);
        acc2 = fmaf(ev.z, wv, acc2);
        acc3 = fmaf(ev.w, wv, acc3);
    }
    h[(nodeBase + 0) * 64 + l] = acc0;
    h[(nodeBase + 1) * 64 + l] = acc1;
    h[(nodeBase + 2) * 64 + l] = acc2;
    h[(nodeBase + 3) * 64 + l] = acc3;
    hb[(nodeBase + 0) * 64 + l] = f2b(acc0);
    hb[(nodeBase + 1) * 64 + l] = f2b(acc1);
    hb[(nodeBase + 2) * 64 + l] = f2b(acc2);
    hb[(nodeBase + 3) * 64 + l] = f2b(acc3);
}

// ---- CSR build: histogram of in-degree into rowptr (pre-zeroed) ----
__global__ __launch_bounds__(256) void hist_kernel(const int* __restrict__ adj, int* __restrict__ rowptr) {
    const int e = blockIdx.x * 256 + threadIdx.x;
    if (e < NE) atomicAdd(&rowptr[adj[2 * e + 1]], 1);
}

// ---- hierarchical exclusive scan over rowptr ----
__global__ __launch_bounds__(256) void scan1_kernel(const int* __restrict__ rowptr, int* __restrict__ bsum) {
    __shared__ int red[256];
    const int t = threadIdx.x, b = blockIdx.x;
    const int base = b * 1024;
    int s = 0;
    for (int i = t; i < 1024; i += 256) {
        const int idx = base + i;
        s += (idx < NN) ? rowptr[idx] : 0;
    }
    red[t] = s;
    __syncthreads();
    for (int off = 128; off > 0; off >>= 1) {
        if (t < off) red[t] += red[t + off];
        __syncthreads();
    }
    if (t == 0) bsum[b] = red[0];
}

__global__ __launch_bounds__(128) void scan2_kernel(int* __restrict__ bsum) {
    __shared__ int s[128];
    const int t = threadIdx.x;
    const int v = (t < SCAN_B) ? bsum[t] : 0;
    s[t] = v;
    __syncthreads();
    for (int off = 1; off < 128; off <<= 1) {
        const int x = (t >= off) ? s[t - off] : 0;
        __syncthreads();
        s[t] += x;
        __syncthreads();
    }
    if (t < SCAN_B) bsum[t] = s[t] - v;  // exclusive
}

__global__ __launch_bounds__(256) void scan3_kernel(int* __restrict__ rowptr, const int* __restrict__ bsum,
                                                    float* __restrict__ deg) {
    __shared__ int red[256];
    const int t = threadIdx.x, b = blockIdx.x;
    const int i0 = b * 1024 + t * 4;
    int v[4];
#pragma unroll
    for (int j = 0; j < 4; ++j) v[j] = (i0 + j < NN) ? rowptr[i0 + j] : 0;
    const int ts = v[0] + v[1] + v[2] + v[3];
    red[t] = ts;
    __syncthreads();
    for (int off = 1; off < 256; off <<= 1) {
        const int x = (t >= off) ? red[t - off] : 0;
        __syncthreads();
        red[t] += x;
        __syncthreads();
    }
    int pre = bsum[b] + red[t] - ts;
#pragma unroll
    for (int j = 0; j < 4; ++j) {
        if (i0 + j < NN) {
            rowptr[i0 + j] = pre;
            deg[i0 + j] = (float)v[j];
            pre += v[j];
        }
    }
}

// ---- CSR build: fill. Uses rowptr as cursor; afterwards rowptr[n] == end offset of node n ----
__global__ __launch_bounds__(256) void fill_kernel(
    const int* __restrict__ adj, int* __restrict__ rowptr, int* __restrict__ csr) {
    const int e = blockIdx.x * 256 + threadIdx.x;
    if (e < NE) {
        const int2 st = ((const int2*)adj)[e];
        const int pos = atomicAdd(&rowptr[st.y], 1);
        csr[pos] = st.x;
    }
}

// ---- aggb[n] = bf16( sum over in-edges of hb[src] ). 8 lanes x 8 bf16 per node. ----
// unroll 8: 8 gather loads in flight per lane on the latency-bound edge loop.
__global__ __launch_bounds__(256) void agg_kernel(
    const int* __restrict__ rowptr, const int* __restrict__ csr,
    const unsigned short* __restrict__ hb, unsigned short* __restrict__ aggb) {
    const int t = threadIdx.x;
    const int node = blockIdx.x * 32 + (t >> 3);
    const int c = t & 7;
    const int start = node ? rowptr[node - 1] : 0;
    const int end = rowptr[node];
    float acc[8];
#pragma unroll
    for (int j = 0; j < 8; ++j) acc[j] = 0.f;
    int e = start;
    for (; e + 7 < end; e += 8) {
        int s[8];
        uint4 u[8];
#pragma unroll
        for (int q = 0; q < 8; ++q) s[q] = csr[e + q];
#pragma unroll
        for (int q = 0; q < 8; ++q) u[q] = *(const uint4*)(hb + s[q] * 64 + c * 8);
#pragma unroll
        for (int q = 0; q < 8; ++q) {
            acc[0] += blo(u[q].x); acc[1] += bhi(u[q].x); acc[2] += blo(u[q].y); acc[3] += bhi(u[q].y);
            acc[4] += blo(u[q].z); acc[5] += bhi(u[q].z); acc[6] += blo(u[q].w); acc[7] += bhi(u[q].w);
        }
    }
    for (; e + 1 < end; e += 2) {
        const int s0 = csr[e], s1 = csr[e + 1];
        const uint4 u0 = *(const uint4*)(hb + s0 * 64 + c * 8);
        const uint4 u1 = *(const uint4*)(hb + s1 * 64 + c * 8);
        acc[0] += blo(u0.x); acc[1] += bhi(u0.x); acc[2] += blo(u0.y); acc[3] += bhi(u0.y);
        acc[4] += blo(u0.z); acc[5] += bhi(u0.z); acc[6] += blo(u0.w); acc[7] += bhi(u0.w);
        acc[0] += blo(u1.x); acc[1] += bhi(u1.x); acc[2] += blo(u1.y); acc[3] += bhi(u1.y);
        acc[4] += blo(u1.z); acc[5] += bhi(u1.z); acc[6] += blo(u1.w); acc[7] += bhi(u1.w);
    }
    if (e < end) {
        const int s0 = csr[e];
        const uint4 u0 = *(const uint4*)(hb + s0 * 64 + c * 8);
        acc[0] += blo(u0.x); acc[1] += bhi(u0.x); acc[2] += blo(u0.y); acc[3] += bhi(u0.y);
        acc[4] += blo(u0.z); acc[5] += bhi(u0.z); acc[6] += blo(u0.w); acc[7] += bhi(u0.w);
    }
    uint4 o;
    o.x = packb(acc[0], acc[1]);
    o.y = packb(acc[2], acc[3]);
    o.z = packb(acc[4], acc[5]);
    o.w = packb(acc[6], acc[7]);
    *(uint4*)(aggb + node * 64 + c * 8) = o;
}

// ---- MFMA GRU v2: one 16-node M-tile per wave (acc = 16 f32x4 -> VGPR <= 128 -> 4 waves/SIMD).
// 512-thr blocks, 64 KB LDS W-stage -> 2 blocks/CU = 16 waves/CU (2x R5 occupancy).
__global__ __launch_bounds__(512) void gru_mfma_kernel(
    float* __restrict__ h, unsigned short* __restrict__ hb,
    const unsigned short* __restrict__ aggb, const float* __restrict__ deg,
    const unsigned short* __restrict__ Wpk, const float* __restrict__ bf,
    const float* __restrict__ bih, const float* __restrict__ bhh) {
    extern __shared__ unsigned short ldsW[];  // 64 frags x 64 lanes x 8 bf16 = 64 KB
    {
        const uint4* src = (const uint4*)Wpk;
        uint4* dst = (uint4*)ldsW;
        for (int i = threadIdx.x; i < 4096; i += 512) dst[i] = src[i];
    }
    __syncthreads();
    const int lane = threadIdx.x & 63;
    const int j0 = lane & 15, quad = lane >> 4;
    const int q8 = quad * 8;
    // bias preload (col = c4*16 + j0 within each 64-wide gate)
    float cr[4], cz[4], cig[4], chg[4], vbfr[4], vbfz[4], vbfg[4];
#pragma unroll
    for (int c4 = 0; c4 < 4; ++c4) {
        const int col = c4 * 16 + j0;
        cr[c4] = bih[col] + bhh[col];
        cz[c4] = bih[64 + col] + bhh[64 + col];
        cig[c4] = bih[128 + col];
        chg[c4] = bhh[128 + col];
        vbfr[c4] = bf[col];
        vbfz[c4] = bf[64 + col];
        vbfg[c4] = bf[128 + col];
    }
    const short8* ldsW8 = (const short8*)ldsW;
    const int gw = blockIdx.x * 8 + (threadIdx.x >> 6);
    const int nw = gridDim.x * 8;

    for (int t = gw; t < NN / 16; t += nw) {
        const int mbase = t * 16;
        const int node0 = mbase + j0;
        short8 a[4];
        a[0] = *(const short8*)(aggb + node0 * 64 + q8);
        a[1] = *(const short8*)(aggb + node0 * 64 + 32 + q8);
        a[2] = *(const short8*)(hb + node0 * 64 + q8);
        a[3] = *(const short8*)(hb + node0 * 64 + 32 + q8);
        f32x4 acc[16];
#pragma unroll
        for (int i = 0; i < 16; ++i) acc[i] = (f32x4){0.f, 0.f, 0.f, 0.f};
#pragma unroll
        for (int nt = 0; nt < 16; ++nt) {
#pragma unroll
            for (int kk = 0; kk < 4; ++kk) {
                acc[nt] = __builtin_amdgcn_mfma_f32_16x16x32_bf16(a[kk], ldsW8[(nt * 4 + kk) * 64 + lane],
                                                                  acc[nt], 0, 0, 0);
            }
        }
        // epilogue (C/D: row=quad*4+reg, col=c4*16+j0)
#pragma unroll
        for (int reg = 0; reg < 4; ++reg) {
            const int node = mbase + quad * 4 + reg;
            const float dg = deg[node];
#pragma unroll
            for (int c4 = 0; c4 < 4; ++c4) {
                const int col = c4 * 16 + j0;
                const float rv = sig1(acc[c4][reg] + cr[c4] + dg * vbfr[c4]);
                const float zv = sig1(acc[4 + c4][reg] + cz[c4] + dg * vbfz[c4]);
                const float gi = acc[8 + c4][reg] + cig[c4] + dg * vbfg[c4];
                const float gh = acc[12 + c4][reg] + chg[c4];
                const float nv = tanh1(fmaf(rv, gh, gi));
                const float hold = h[node * 64 + col];
                const float hn = (1.f - zv) * nv + zv * hold;
                h[node * 64 + col] = hn;
                hb[node * 64 + col] = f2b(hn);
            }
        }
    }
}

// ---- X[b, g*64 + j] = h[prop[b]][j] ----
__global__ __launch_bounds__(256) void gather_kernel(
    const int* __restrict__ prop, const float* __restrict__ h, float* __restrict__ X, int g) {
    const int b = blockIdx.x * 4 + (threadIdx.x >> 6);
    const int j = threadIdx.x & 63;
    X[b * 128 + g * 64 + j] = h[prop[b] * 64 + j];
}

// ---- hidden = relu(X@W1+b1); z = hidden@W2+b2; out[b]=sigmoid(z); zbuf[b]=z ----
__global__ __launch_bounds__(256) void mlp_kernel(
    const float* __restrict__ X, const float* __restrict__ W1, const float* __restrict__ b1,
    const float* __restrict__ W2, const float* __restrict__ b2,
    float* __restrict__ out, float* __restrict__ zbuf) {
    const int b = blockIdx.x * 4 + (threadIdx.x >> 6);
    const int j = threadIdx.x & 63;
    const float* x = X + b * 128;
    float acc = b1[j];
#pragma unroll 4
    for (int k = 0; k < 128; ++k) acc = fmaf(x[k], W1[k * 64 + j], acc);
    float v = fmaxf(acc, 0.f) * W2[j];
#pragma unroll
    for (int off = 32; off > 0; off >>= 1) v += __shfl_down(v, off);
    if (j == 0) {
        const float z = v + b2[0];
        out[b] = 1.f / (1.f + expf(-z));
        zbuf[b] = z;
    }
}

// ---- loss = -mean(y*logsig(z) + (1-y)*logsig(-z)) -> out[BT] ----
__global__ __launch_bounds__(256) void loss_kernel(
    const float* __restrict__ zbuf, const int* __restrict__ labels, float* __restrict__ out) {
    __shared__ float red[256];
    const int t = threadIdx.x;
    float s = 0.f;
    for (int i = t; i < BT; i += 256) {
        const float z = zbuf[i];
        const float y = (float)labels[i];
        const float lsp = (z >= 0.f) ? -log1pf(expf(-z)) : (z - log1pf(expf(z)));
        const float lsn = lsp - z;
        s += y * lsp + (1.f - y) * lsn;
    }
    red[t] = s;
    __syncthreads();
    for (int off = 128; off > 0; off >>= 1) {
        if (t < off) red[t] += red[t + off];
        __syncthreads();
    }
    if (t == 0) out[BT] = -red[0] / (float)BT;
}

extern "C" void kernel_launch(void* const* d_in, const int* in_sizes, int n_in,
                              void* d_out, int out_size, void* d_ws, size_t ws_size,
                              hipStream_t stream) {
    char* ws = (char*)d_ws;
    float* h = (float*)(ws);                                  // 25,600,000 B
    unsigned short* hb = (unsigned short*)(ws + 25600000);    // 12,800,000 B
    unsigned short* aggb = (unsigned short*)(ws + 38400000);  // 12,800,000 B
    float* deg = (float*)(ws + 51200000);                     // 400,000 B
    float* Wf = (float*)(ws + 51600000);                      // 98,304 B
    float* bf = (float*)(ws + 51698304);                      // 1,536 B
    int* rowptr = (int*)(ws + 51699840);                      // 400,000 B
    int* csr = (int*)(ws + 52099840);                         // 4,800,000 B
    int* bsum = (int*)(ws + 56899840);                        // 512 B
    float* X = (float*)(ws + 56900352);                       // 2,097,152 B
    float* zbuf = (float*)(ws + 58997504);                    // 16,384 B
    unsigned short* Wpk = (unsigned short*)(ws + 59013888);   // 131,072 B
    float* out = (float*)d_out;

    const float* emb_table = (const float*)d_in[7];
    const float* Wp = (const float*)d_in[8];
    const float* bp = (const float*)d_in[9];

    fusew_kernel<<<16, 256, 65536, stream>>>(
        (const float*)d_in[10], (const float*)d_in[12], (const float*)d_in[11],
        (const float*)d_in[16], (const float*)d_in[18], (const float*)d_in[17], Wf, bf);
    wpack_kernel<<<128, 64, 0, stream>>>(Wf, (const float*)d_in[13], (const float*)d_in[19], Wpk);

    for (int g = 0; g < 2; ++g) {
        const int* adjg = (const int*)d_in[2 + g];
        // CSR build for this graph
        hipMemsetAsync(rowptr, 0, (size_t)NN * 4, stream);
        hist_kernel<<<(NE + 255) / 256, 256, 0, stream>>>(adjg, rowptr);
        scan1_kernel<<<SCAN_B, 256, 0, stream>>>(rowptr, bsum);
        scan2_kernel<<<1, 128, 0, stream>>>(bsum);
        scan3_kernel<<<SCAN_B, 256, 0, stream>>>(rowptr, bsum, deg);
        fill_kernel<<<(NE + 255) / 256, 256, 0, stream>>>(adjg, rowptr, csr);

        embed_kernel<<<NN / 16, 256, 0, stream>>>((const int*)d_in[g], emb_table, Wp, bp, h, hb);
        for (int l = 0; l < 2; ++l) {
            const float* bih = (const float*)d_in[14 + 6 * l];
            const float* bhh = (const float*)d_in[15 + 6 * l];
            for (int ts = 0; ts < 3; ++ts) {
                agg_kernel<<<NN / 32, 256, 0, stream>>>(rowptr, csr, hb, aggb);
                gru_mfma_kernel<<<512, 512, 65536, stream>>>(h, hb, aggb, deg, Wpk + l * 32768,
                                                             bf + l * 192, bih, bhh);
            }
        }
        gather_kernel<<<BT / 4, 256, 0, stream>>>((const int*)d_in[4 + g], h, X, g);
    }
    mlp_kernel<<<BT / 4, 256, 0, stream>>>(X, (const float*)d_in[22], (const float*)d_in[23],
                                           (const float*)d_in[24], (const float*)d_in[25], out, zbuf);
    loss_kernel<<<1, 256, 0, stream>>>(zbuf, (const int*)d_in[6], out);
}

// Round 8
// 1422.022 us; speedup vs baseline: 1.4928x; 1.4817x over previous
//
#include <hip/hip_runtime.h>
#include <math.h>

#define NN 100000
#define NE 1200000
#define EMBD 100
#define HD 64
#define BT 4096
#define SCAN_B 98  // 98 * 1024 >= NN

typedef __attribute__((ext_vector_type(8))) short short8;  // 8 bf16 (4 VGPRs)
typedef __attribute__((ext_vector_type(4))) float f32x4;   // MFMA C/D

__device__ __forceinline__ float sig1(float x) { return 1.f / (1.f + __expf(-x)); }
__device__ __forceinline__ float tanh1(float x) {
    x = fminf(fmaxf(x, -15.f), 15.f);
    float e = __expf(2.f * x);
    return (e - 1.f) / (e + 1.f);
}
// f32 -> bf16 (round-to-nearest-even), and bf16 -> f32 unpack helpers
__device__ __forceinline__ unsigned short f2b(float f) {
    unsigned u = __float_as_uint(f);
    u += 0x7fffu + ((u >> 16) & 1u);
    return (unsigned short)(u >> 16);
}
__device__ __forceinline__ float b2f(unsigned short s) { return __uint_as_float(((unsigned)s) << 16); }
__device__ __forceinline__ float blo(unsigned u) { return __uint_as_float(u << 16); }
__device__ __forceinline__ float bhi(unsigned u) { return __uint_as_float(u & 0xffff0000u); }
__device__ __forceinline__ unsigned packb(float lo, float hi) {
    return (unsigned)f2b(lo) | ((unsigned)f2b(hi) << 16);
}

// ---- precompute Wf[l] = Wm[l] @ Wih[l] (64x192), bf[l] = bm[l] @ Wih[l] (192) ----
__global__ __launch_bounds__(256) void fusew_kernel(
    const float* __restrict__ Wm0, const float* __restrict__ Wih0, const float* __restrict__ bm0,
    const float* __restrict__ Wm1, const float* __restrict__ Wih1, const float* __restrict__ bm1,
    float* __restrict__ Wf, float* __restrict__ bf) {
    extern __shared__ float lds[];
    float* wm_s = lds;          // 4096
    float* wih_s = lds + 4096;  // 12288
    const int l = blockIdx.x >> 3, slice = blockIdx.x & 7;
    const float* Wm = l ? Wm1 : Wm0;
    const float* Wih = l ? Wih1 : Wih0;
    const float* bm = l ? bm1 : bm0;
    for (int i = threadIdx.x; i < 4096; i += 256) wm_s[i] = Wm[i];
    for (int i = threadIdx.x; i < 12288; i += 256) wih_s[i] = Wih[i];
    __syncthreads();
    float* Wfl = Wf + l * 12288;
    float* bfl = bf + l * 192;
    const int o0 = slice * 1536;
    for (int o = o0 + threadIdx.x; o < o0 + 1536; o += 256) {
        int r = o / 192, c = o % 192;
        float s = 0.f;
        for (int k = 0; k < 64; ++k) s = fmaf(wm_s[r * 64 + k], wih_s[k * 192 + c], s);
        Wfl[o] = s;
    }
    const int c0 = slice * 24;
    for (int c = c0 + threadIdx.x; c < c0 + 24; c += 256) {
        float s = 0.f;
        for (int k = 0; k < 64; ++k) s = fmaf(bm[k], wih_s[k * 192 + c], s);
        bfl[c] = s;
    }
}

// ---- pack W' (128x256) into MFMA B-fragment order, bf16 (layout verified in R5) ----
__global__ __launch_bounds__(64) void wpack_kernel(
    const float* __restrict__ Wf, const float* __restrict__ Whh0, const float* __restrict__ Whh1,
    unsigned short* __restrict__ Wpk) {
    const int b = blockIdx.x;  // 0..127
    const int l = b >> 6, frag = b & 63;
    const int nt = frag >> 2, kk = frag & 3;
    const int lane = threadIdx.x;
    const int n = nt * 16 + (lane & 15);
    const int g = n >> 6, j = n & 63;
    const int k0 = kk * 32 + (lane >> 4) * 8;
    const float* wf = Wf + l * 12288;
    const float* whh = l ? Whh1 : Whh0;
    unsigned short o[8];
#pragma unroll
    for (int jj = 0; jj < 8; ++jj) {
        const int k = k0 + jj;
        float v = 0.f;
        if (k < 64) {
            if (g == 0) v = wf[k * 192 + j];
            else if (g == 1) v = wf[k * 192 + 64 + j];
            else if (g == 2) v = wf[k * 192 + 128 + j];
        } else {
            const int k2 = k - 64;
            if (g == 0) v = whh[k2 * 192 + j];
            else if (g == 1) v = whh[k2 * 192 + 64 + j];
            else if (g == 3) v = whh[k2 * 192 + 128 + j];
        }
        o[jj] = f2b(v);
    }
    *(uint4*)(Wpk + ((size_t)(l * 64 + frag) * 64 + lane) * 8) = *(const uint4*)o;
}

// ---- hb[n] = bf16( emb_table[ind[n]] @ Wp + bp ) ----
__global__ __launch_bounds__(256) void embed_kernel(
    const int* __restrict__ ind, const float* __restrict__ emb,
    const float* __restrict__ Wp, const float* __restrict__ bp,
    unsigned short* __restrict__ hb) {
    __shared__ float et[4][EMBD][4];  // [wave][k][node]
    const int w = threadIdx.x >> 6;
    const int l = threadIdx.x & 63;
    const int nodeBase = blockIdx.x * 16 + w * 4;
    for (int f = l; f < 100; f += 64) {
        const int n = f / 25, c = f % 25;
        const int idx = ind[nodeBase + n];
        const float4 v = *(const float4*)(emb + (size_t)idx * EMBD + c * 4);
        et[w][c * 4 + 0][n] = v.x;
        et[w][c * 4 + 1][n] = v.y;
        et[w][c * 4 + 2][n] = v.z;
        et[w][c * 4 + 3][n] = v.w;
    }
    __syncthreads();
    float acc0 = bp[l], acc1 = acc0, acc2 = acc0, acc3 = acc0;
#pragma unroll 5
    for (int k = 0; k < EMBD; ++k) {
        const float wv = Wp[k * 64 + l];
        const float4 ev = *(const float4*)&et[w][k][0];
        acc0 = fmaf(ev.x, wv, acc0);
        acc1 = fmaf(ev.y, wv, acc1);
        acc2 = fmaf(ev.z, wv, acc2);
        acc3 = fmaf(ev.w, wv, acc3);
    }
    hb[(nodeBase + 0) * 64 + l] = f2b(acc0);
    hb[(nodeBase + 1) * 64 + l] = f2b(acc1);
    hb[(nodeBase + 2) * 64 + l] = f2b(acc2);
    hb[(nodeBase + 3) * 64 + l] = f2b(acc3);
}

// ---- CSR build: histogram of in-degree into rowptr (pre-zeroed) ----
__global__ __launch_bounds__(256) void hist_kernel(const int* __restrict__ adj, int* __restrict__ rowptr) {
    const int e = blockIdx.x * 256 + threadIdx.x;
    if (e < NE) atomicAdd(&rowptr[adj[2 * e + 1]], 1);
}

// ---- hierarchical exclusive scan over rowptr ----
__global__ __launch_bounds__(256) void scan1_kernel(const int* __restrict__ rowptr, int* __restrict__ bsum) {
    __shared__ int red[256];
    const int t = threadIdx.x, b = blockIdx.x;
    const int base = b * 1024;
    int s = 0;
    for (int i = t; i < 1024; i += 256) {
        const int idx = base + i;
        s += (idx < NN) ? rowptr[idx] : 0;
    }
    red[t] = s;
    __syncthreads();
    for (int off = 128; off > 0; off >>= 1) {
        if (t < off) red[t] += red[t + off];
        __syncthreads();
    }
    if (t == 0) bsum[b] = red[0];
}

__global__ __launch_bounds__(128) void scan2_kernel(int* __restrict__ bsum) {
    __shared__ int s[128];
    const int t = threadIdx.x;
    const int v = (t < SCAN_B) ? bsum[t] : 0;
    s[t] = v;
    __syncthreads();
    for (int off = 1; off < 128; off <<= 1) {
        const int x = (t >= off) ? s[t - off] : 0;
        __syncthreads();
        s[t] += x;
        __syncthreads();
    }
    if (t < SCAN_B) bsum[t] = s[t] - v;  // exclusive
}

__global__ __launch_bounds__(256) void scan3_kernel(int* __restrict__ rowptr, const int* __restrict__ bsum,
                                                    float* __restrict__ deg) {
    __shared__ int red[256];
    const int t = threadIdx.x, b = blockIdx.x;
    const int i0 = b * 1024 + t * 4;
    int v[4];
#pragma unroll
    for (int j = 0; j < 4; ++j) v[j] = (i0 + j < NN) ? rowptr[i0 + j] : 0;
    const int ts = v[0] + v[1] + v[2] + v[3];
    red[t] = ts;
    __syncthreads();
    for (int off = 1; off < 256; off <<= 1) {
        const int x = (t >= off) ? red[t - off] : 0;
        __syncthreads();
        red[t] += x;
        __syncthreads();
    }
    int pre = bsum[b] + red[t] - ts;
#pragma unroll
    for (int j = 0; j < 4; ++j) {
        if (i0 + j < NN) {
            rowptr[i0 + j] = pre;
            deg[i0 + j] = (float)v[j];
            pre += v[j];
        }
    }
}

// ---- CSR build: fill. Uses rowptr as cursor; afterwards rowptr[n] == end offset of node n ----
__global__ __launch_bounds__(256) void fill_kernel(
    const int* __restrict__ adj, int* __restrict__ rowptr, int* __restrict__ csr) {
    const int e = blockIdx.x * 256 + threadIdx.x;
    if (e < NE) {
        const int2 st = ((const int2*)adj)[e];
        const int pos = atomicAdd(&rowptr[st.y], 1);
        csr[pos] = st.x;
    }
}

// ---- aggb[n] = bf16( sum over in-edges of hb[src] ). 8 lanes x 8 bf16 per node. ----
__global__ __launch_bounds__(256) void agg_kernel(
    const int* __restrict__ rowptr, const int* __restrict__ csr,
    const unsigned short* __restrict__ hb, unsigned short* __restrict__ aggb) {
    const int t = threadIdx.x;
    const int node = blockIdx.x * 32 + (t >> 3);
    const int c = t & 7;
    const int start = node ? rowptr[node - 1] : 0;
    const int end = rowptr[node];
    float acc[8];
#pragma unroll
    for (int j = 0; j < 8; ++j) acc[j] = 0.f;
    int e = start;
    for (; e + 7 < end; e += 8) {
        int s[8];
        uint4 u[8];
#pragma unroll
        for (int q = 0; q < 8; ++q) s[q] = csr[e + q];
#pragma unroll
        for (int q = 0; q < 8; ++q) u[q] = *(const uint4*)(hb + s[q] * 64 + c * 8);
#pragma unroll
        for (int q = 0; q < 8; ++q) {
            acc[0] += blo(u[q].x); acc[1] += bhi(u[q].x); acc[2] += blo(u[q].y); acc[3] += bhi(u[q].y);
            acc[4] += blo(u[q].z); acc[5] += bhi(u[q].z); acc[6] += blo(u[q].w); acc[7] += bhi(u[q].w);
        }
    }
    for (; e + 1 < end; e += 2) {
        const int s0 = csr[e], s1 = csr[e + 1];
        const uint4 u0 = *(const uint4*)(hb + s0 * 64 + c * 8);
        const uint4 u1 = *(const uint4*)(hb + s1 * 64 + c * 8);
        acc[0] += blo(u0.x); acc[1] += bhi(u0.x); acc[2] += blo(u0.y); acc[3] += bhi(u0.y);
        acc[4] += blo(u0.z); acc[5] += bhi(u0.z); acc[6] += blo(u0.w); acc[7] += bhi(u0.w);
        acc[0] += blo(u1.x); acc[1] += bhi(u1.x); acc[2] += blo(u1.y); acc[3] += bhi(u1.y);
        acc[4] += blo(u1.z); acc[5] += bhi(u1.z); acc[6] += blo(u1.w); acc[7] += bhi(u1.w);
    }
    if (e < end) {
        const int s0 = csr[e];
        const uint4 u0 = *(const uint4*)(hb + s0 * 64 + c * 8);
        acc[0] += blo(u0.x); acc[1] += bhi(u0.x); acc[2] += blo(u0.y); acc[3] += bhi(u0.y);
        acc[4] += blo(u0.z); acc[5] += bhi(u0.z); acc[6] += blo(u0.w); acc[7] += bhi(u0.w);
    }
    uint4 o;
    o.x = packb(acc[0], acc[1]);
    o.y = packb(acc[2], acc[3]);
    o.z = packb(acc[4], acc[5]);
    o.w = packb(acc[6], acc[7]);
    *(uint4*)(aggb + node * 64 + c * 8) = o;
}

// ---- MFMA GRU v3: R5 shape (256 thr, 2 M-tiles/wave), bf16 state only.
// hb updated in place: each 16-node tile owned by exactly one wave; reads (A-frags,
// hold) precede writes in program order. No fp32 h at all.
__global__ __launch_bounds__(256) void gru_mfma_kernel(
    unsigned short* __restrict__ hb, const unsigned short* __restrict__ aggb,
    const float* __restrict__ deg, const unsigned short* __restrict__ Wpk,
    const float* __restrict__ bf, const float* __restrict__ bih, const float* __restrict__ bhh) {
    extern __shared__ unsigned short ldsW[];  // 64 frags x 64 lanes x 8 bf16 = 64 KB
    {
        const uint4* src = (const uint4*)Wpk;
        uint4* dst = (uint4*)ldsW;
        for (int i = threadIdx.x; i < 4096; i += 256) dst[i] = src[i];
    }
    __syncthreads();
    const int lane = threadIdx.x & 63;
    const int j0 = lane & 15, quad = lane >> 4;
    const int q8 = quad * 8;
    // bias preload (col = c4*16 + j0 within each 64-wide gate)
    float cr[4], cz[4], cig[4], chg[4], vbfr[4], vbfz[4], vbfg[4];
#pragma unroll
    for (int c4 = 0; c4 < 4; ++c4) {
        const int col = c4 * 16 + j0;
        cr[c4] = bih[col] + bhh[col];
        cz[c4] = bih[64 + col] + bhh[64 + col];
        cig[c4] = bih[128 + col];
        chg[c4] = bhh[128 + col];
        vbfr[c4] = bf[col];
        vbfz[c4] = bf[64 + col];
        vbfg[c4] = bf[128 + col];
    }
    const short8* ldsW8 = (const short8*)ldsW;
    const int gw = blockIdx.x * 4 + (threadIdx.x >> 6);
    const int nw = gridDim.x * 4;

    auto epilogue = [&](const f32x4(&acc)[16], int nb) {
#pragma unroll
        for (int reg = 0; reg < 4; ++reg) {
            const int node = nb + reg;
            const float dg = deg[node];
#pragma unroll
            for (int c4 = 0; c4 < 4; ++c4) {
                const int col = c4 * 16 + j0;
                const float rv = sig1(acc[c4][reg] + cr[c4] + dg * vbfr[c4]);
                const float zv = sig1(acc[4 + c4][reg] + cz[c4] + dg * vbfz[c4]);
                const float gi = acc[8 + c4][reg] + cig[c4] + dg * vbfg[c4];
                const float gh = acc[12 + c4][reg] + chg[c4];
                const float nv = tanh1(fmaf(rv, gh, gi));
                const float hold = b2f(hb[node * 64 + col]);  // L1-hot (tile just read)
                const float hn = (1.f - zv) * nv + zv * hold;
                hb[node * 64 + col] = f2b(hn);
            }
        }
    };

    for (int t = gw; t < NN / 32; t += nw) {
        const int mbase = t * 32;
        const int node0 = mbase + j0, node1 = node0 + 16;
        short8 a[4], b[4];
        a[0] = *(const short8*)(aggb + node0 * 64 + q8);
        a[1] = *(const short8*)(aggb + node0 * 64 + 32 + q8);
        a[2] = *(const short8*)(hb + node0 * 64 + q8);
        a[3] = *(const short8*)(hb + node0 * 64 + 32 + q8);
        b[0] = *(const short8*)(aggb + node1 * 64 + q8);
        b[1] = *(const short8*)(aggb + node1 * 64 + 32 + q8);
        b[2] = *(const short8*)(hb + node1 * 64 + q8);
        b[3] = *(const short8*)(hb + node1 * 64 + 32 + q8);
        f32x4 acc0[16], acc1[16];
#pragma unroll
        for (int i = 0; i < 16; ++i) {
            acc0[i] = (f32x4){0.f, 0.f, 0.f, 0.f};
            acc1[i] = (f32x4){0.f, 0.f, 0.f, 0.f};
        }
#pragma unroll
        for (int nt = 0; nt < 16; ++nt) {
#pragma unroll
            for (int kk = 0; kk < 4; ++kk) {
                const short8 w = ldsW8[(nt * 4 + kk) * 64 + lane];
                acc0[nt] = __builtin_amdgcn_mfma_f32_16x16x32_bf16(a[kk], w, acc0[nt], 0, 0, 0);
                acc1[nt] = __builtin_amdgcn_mfma_f32_16x16x32_bf16(b[kk], w, acc1[nt], 0, 0, 0);
            }
        }
        epilogue(acc0, mbase + quad * 4);
        epilogue(acc1, mbase + 16 + quad * 4);
    }
}

// ---- X[b, g*64 + j] = f32(hb[prop[b]][j]) ----
__global__ __launch_bounds__(256) void gather_kernel(
    const int* __restrict__ prop, const unsigned short* __restrict__ hb, float* __restrict__ X, int g) {
    const int b = blockIdx.x * 4 + (threadIdx.x >> 6);
    const int j = threadIdx.x & 63;
    X[b * 128 + g * 64 + j] = b2f(hb[prop[b] * 64 + j]);
}

// ---- hidden = relu(X@W1+b1); z = hidden@W2+b2; out[b]=sigmoid(z); zbuf[b]=z ----
__global__ __launch_bounds__(256) void mlp_kernel(
    const float* __restrict__ X, const float* __restrict__ W1, const float* __restrict__ b1,
    const float* __restrict__ W2, const float* __restrict__ b2,
    float* __restrict__ out, float* __restrict__ zbuf) {
    const int b = blockIdx.x * 4 + (threadIdx.x >> 6);
    const int j = threadIdx.x & 63;
    const float* x = X + b * 128;
    float acc = b1[j];
#pragma unroll 4
    for (int k = 0; k < 128; ++k) acc = fmaf(x[k], W1[k * 64 + j], acc);
    float v = fmaxf(acc, 0.f) * W2[j];
#pragma unroll
    for (int off = 32; off > 0; off >>= 1) v += __shfl_down(v, off);
    if (j == 0) {
        const float z = v + b2[0];
        out[b] = 1.f / (1.f + expf(-z));
        zbuf[b] = z;
    }
}

// ---- loss = -mean(y*logsig(z) + (1-y)*logsig(-z)) -> out[BT] ----
__global__ __launch_bounds__(256) void loss_kernel(
    const float* __restrict__ zbuf, const int* __restrict__ labels, float* __restrict__ out) {
    __shared__ float red[256];
    const int t = threadIdx.x;
    float s = 0.f;
    for (int i = t; i < BT; i += 256) {
        const float z = zbuf[i];
        const float y = (float)labels[i];
        const float lsp = (z >= 0.f) ? -log1pf(expf(-z)) : (z - log1pf(expf(z)));
        const float lsn = lsp - z;
        s += y * lsp + (1.f - y) * lsn;
    }
    red[t] = s;
    __syncthreads();
    for (int off = 128; off > 0; off >>= 1) {
        if (t < off) red[t] += red[t + off];
        __syncthreads();
    }
    if (t == 0) out[BT] = -red[0] / (float)BT;
}

extern "C" void kernel_launch(void* const* d_in, const int* in_sizes, int n_in,
                              void* d_out, int out_size, void* d_ws, size_t ws_size,
                              hipStream_t stream) {
    char* ws = (char*)d_ws;
    unsigned short* hb = (unsigned short*)(ws);               // 12,800,000 B
    unsigned short* aggb = (unsigned short*)(ws + 12800000);  // 12,800,000 B
    float* deg = (float*)(ws + 25600000);                     // 400,000 B
    float* Wf = (float*)(ws + 26000000);                      // 98,304 B
    float* bf = (float*)(ws + 26098304);                      // 1,536 B
    int* rowptr = (int*)(ws + 26099840);                      // 400,000 B
    int* csr = (int*)(ws + 26499840);                         // 4,800,000 B
    int* bsum = (int*)(ws + 31299840);                        // 512 B
    float* X = (float*)(ws + 31300352);                       // 2,097,152 B
    float* zbuf = (float*)(ws + 33397504);                    // 16,384 B
    unsigned short* Wpk = (unsigned short*)(ws + 33413888);   // 131,072 B
    float* out = (float*)d_out;

    const float* emb_table = (const float*)d_in[7];
    const float* Wp = (const float*)d_in[8];
    const float* bp = (const float*)d_in[9];

    fusew_kernel<<<16, 256, 65536, stream>>>(
        (const float*)d_in[10], (const float*)d_in[12], (const float*)d_in[11],
        (const float*)d_in[16], (const float*)d_in[18], (const float*)d_in[17], Wf, bf);
    wpack_kernel<<<128, 64, 0, stream>>>(Wf, (const float*)d_in[13], (const float*)d_in[19], Wpk);

    for (int g = 0; g < 2; ++g) {
        const int* adjg = (const int*)d_in[2 + g];
        // CSR build for this graph
        hipMemsetAsync(rowptr, 0, (size_t)NN * 4, stream);
        hist_kernel<<<(NE + 255) / 256, 256, 0, stream>>>(adjg, rowptr);
        scan1_kernel<<<SCAN_B, 256, 0, stream>>>(rowptr, bsum);
        scan2_kernel<<<1, 128, 0, stream>>>(bsum);
        scan3_kernel<<<SCAN_B, 256, 0, stream>>>(rowptr, bsum, deg);
        fill_kernel<<<(NE + 255) / 256, 256, 0, stream>>>(adjg, rowptr, csr);

        embed_kernel<<<NN / 16, 256, 0, stream>>>((const int*)d_in[g], emb_table, Wp, bp, hb);
        for (int l = 0; l < 2; ++l) {
            const float* bih = (const float*)d_in[14 + 6 * l];
            const float* bhh = (const float*)d_in[15 + 6 * l];
            for (int ts = 0; ts < 3; ++ts) {
                agg_kernel<<<NN / 32, 256, 0, stream>>>(rowptr, csr, hb, aggb);
                gru_mfma_kernel<<<512, 256, 65536, stream>>>(hb, aggb, deg, Wpk + l * 32768,
                                                             bf + l * 192, bih, bhh);
            }
        }
        gather_kernel<<<BT / 4, 256, 0, stream>>>((const int*)d_in[4 + g], hb, X, g);
    }
    mlp_kernel<<<BT / 4, 256, 0, stream>>>(X, (const float*)d_in[22], (const float*)d_in[23],
                                           (const float*)d_in[24], (const float*)d_in[25], out, zbuf);
    loss_kernel<<<1, 256, 0, stream>>>(zbuf, (const int*)d_in[6], out);
}

// Round 9
// 1384.191 us; speedup vs baseline: 1.5336x; 1.0273x over previous
//
#include <hip/hip_runtime.h>
#include <math.h>

#define NN 100000
#define NE 1200000
#define EMBD 100
#define HD 64
#define BT 4096
#define SCAN_B 98  // 98 * 1024 >= NN

typedef __attribute__((ext_vector_type(8))) short short8;  // 8 bf16 (4 VGPRs)
typedef __attribute__((ext_vector_type(4))) float f32x4;   // MFMA C/D
typedef __attribute__((ext_vector_type(2))) float f32x2;   // fp8 pk-cvt result

__device__ __forceinline__ float sig1(float x) { return 1.f / (1.f + __expf(-x)); }
__device__ __forceinline__ float tanh1(float x) {
    x = fminf(fmaxf(x, -15.f), 15.f);
    float e = __expf(2.f * x);
    return (e - 1.f) / (e + 1.f);
}
// f32 -> bf16 (round-to-nearest-even), and bf16 -> f32 unpack helpers
__device__ __forceinline__ unsigned short f2b(float f) {
    unsigned u = __float_as_uint(f);
    u += 0x7fffu + ((u >> 16) & 1u);
    return (unsigned short)(u >> 16);
}
__device__ __forceinline__ float b2f(unsigned short s) { return __uint_as_float(((unsigned)s) << 16); }
__device__ __forceinline__ float blo(unsigned u) { return __uint_as_float(u << 16); }
__device__ __forceinline__ float bhi(unsigned u) { return __uint_as_float(u & 0xffff0000u); }
__device__ __forceinline__ unsigned packb(float lo, float hi) {
    return (unsigned)f2b(lo) | ((unsigned)f2b(hi) << 16);
}
// fp8 e4m3 (OCP on gfx950) HW pack/unpack. hb8 row layout permutation:
// byte p of a row holds feature col(p) = (p&3)*16 + (p>>2)  [baked into wpack]
__device__ __forceinline__ unsigned pk8(float a, float b, float c, float d) {
    int w = 0;
    w = __builtin_amdgcn_cvt_pk_fp8_f32(a, b, w, false);
    w = __builtin_amdgcn_cvt_pk_fp8_f32(c, d, w, true);
    return (unsigned)w;
}

// ---- precompute Wf[l] = Wm[l] @ Wih[l] (64x192), bf[l] = bm[l] @ Wih[l] (192) ----
__global__ __launch_bounds__(256) void fusew_kernel(
    const float* __restrict__ Wm0, const float* __restrict__ Wih0, const float* __restrict__ bm0,
    const float* __restrict__ Wm1, const float* __restrict__ Wih1, const float* __restrict__ bm1,
    float* __restrict__ Wf, float* __restrict__ bf) {
    extern __shared__ float lds[];
    float* wm_s = lds;          // 4096
    float* wih_s = lds + 4096;  // 12288
    const int l = blockIdx.x >> 3, slice = blockIdx.x & 7;
    const float* Wm = l ? Wm1 : Wm0;
    const float* Wih = l ? Wih1 : Wih0;
    const float* bm = l ? bm1 : bm0;
    for (int i = threadIdx.x; i < 4096; i += 256) wm_s[i] = Wm[i];
    for (int i = threadIdx.x; i < 12288; i += 256) wih_s[i] = Wih[i];
    __syncthreads();
    float* Wfl = Wf + l * 12288;
    float* bfl = bf + l * 192;
    const int o0 = slice * 1536;
    for (int o = o0 + threadIdx.x; o < o0 + 1536; o += 256) {
        int r = o / 192, c = o % 192;
        float s = 0.f;
        for (int k = 0; k < 64; ++k) s = fmaf(wm_s[r * 64 + k], wih_s[k * 192 + c], s);
        Wfl[o] = s;
    }
    const int c0 = slice * 24;
    for (int c = c0 + threadIdx.x; c < c0 + 24; c += 256) {
        float s = 0.f;
        for (int k = 0; k < 64; ++k) s = fmaf(bm[k], wih_s[k * 192 + c], s);
        bfl[c] = s;
    }
}

// ---- pack W' (128x256) into MFMA B-fragment order, bf16.
// agg half (k<64) uses PERMUTED Wf rows: aggb element k holds feature (k&3)*16+(k>>2).
__global__ __launch_bounds__(64) void wpack_kernel(
    const float* __restrict__ Wf, const float* __restrict__ Whh0, const float* __restrict__ Whh1,
    unsigned short* __restrict__ Wpk) {
    const int b = blockIdx.x;  // 0..127
    const int l = b >> 6, frag = b & 63;
    const int nt = frag >> 2, kk = frag & 3;
    const int lane = threadIdx.x;
    const int n = nt * 16 + (lane & 15);
    const int g = n >> 6, j = n & 63;
    const int k0 = kk * 32 + (lane >> 4) * 8;
    const float* wf = Wf + l * 12288;
    const float* whh = l ? Whh1 : Whh0;
    unsigned short o[8];
#pragma unroll
    for (int jj = 0; jj < 8; ++jj) {
        const int k = k0 + jj;
        float v = 0.f;
        if (k < 64) {
            const int kp = (k & 3) * 16 + (k >> 2);  // fp8-gather layout permutation
            if (g == 0) v = wf[kp * 192 + j];
            else if (g == 1) v = wf[kp * 192 + 64 + j];
            else if (g == 2) v = wf[kp * 192 + 128 + j];
        } else {
            const int k2 = k - 64;
            if (g == 0) v = whh[k2 * 192 + j];
            else if (g == 1) v = whh[k2 * 192 + 64 + j];
            else if (g == 3) v = whh[k2 * 192 + 128 + j];
        }
        o[jj] = f2b(v);
    }
    *(uint4*)(Wpk + ((size_t)(l * 64 + frag) * 64 + lane) * 8) = *(const uint4*)o;
}

// ---- hb[n] = bf16( emb_table[ind[n]] @ Wp + bp ), plus fp8 mirror hb8 ----
__global__ __launch_bounds__(256) void embed_kernel(
    const int* __restrict__ ind, const float* __restrict__ emb,
    const float* __restrict__ Wp, const float* __restrict__ bp,
    unsigned short* __restrict__ hb, unsigned char* __restrict__ hb8) {
    __shared__ float et[4][EMBD][4];  // [wave][k][node]
    const int w = threadIdx.x >> 6;
    const int l = threadIdx.x & 63;
    const int nodeBase = blockIdx.x * 16 + w * 4;
    for (int f = l; f < 100; f += 64) {
        const int n = f / 25, c = f % 25;
        const int idx = ind[nodeBase + n];
        const float4 v = *(const float4*)(emb + (size_t)idx * EMBD + c * 4);
        et[w][c * 4 + 0][n] = v.x;
        et[w][c * 4 + 1][n] = v.y;
        et[w][c * 4 + 2][n] = v.z;
        et[w][c * 4 + 3][n] = v.w;
    }
    __syncthreads();
    float acc[4];
    acc[0] = bp[l]; acc[1] = acc[0]; acc[2] = acc[0]; acc[3] = acc[0];
#pragma unroll 5
    for (int k = 0; k < EMBD; ++k) {
        const float wv = Wp[k * 64 + l];
        const float4 ev = *(const float4*)&et[w][k][0];
        acc[0] = fmaf(ev.x, wv, acc[0]);
        acc[1] = fmaf(ev.y, wv, acc[1]);
        acc[2] = fmaf(ev.z, wv, acc[2]);
        acc[3] = fmaf(ev.w, wv, acc[3]);
    }
#pragma unroll
    for (int n = 0; n < 4; ++n) {
        hb[(nodeBase + n) * 64 + l] = f2b(acc[n]);
        // fp8 mirror: word j (j<16) holds cols {j, j+16, j+32, j+48}
        const float v0 = __shfl(acc[n], l & 15);
        const float v1 = __shfl(acc[n], (l & 15) + 16);
        const float v2 = __shfl(acc[n], (l & 15) + 32);
        const float v3 = __shfl(acc[n], (l & 15) + 48);
        if (l < 16) ((unsigned*)(hb8 + (size_t)(nodeBase + n) * 64))[l] = pk8(v0, v1, v2, v3);
    }
}

// ---- CSR build: histogram of in-degree into rowptr (pre-zeroed) ----
__global__ __launch_bounds__(256) void hist_kernel(const int* __restrict__ adj, int* __restrict__ rowptr) {
    const int e = blockIdx.x * 256 + threadIdx.x;
    if (e < NE) atomicAdd(&rowptr[adj[2 * e + 1]], 1);
}

// ---- hierarchical exclusive scan over rowptr ----
__global__ __launch_bounds__(256) void scan1_kernel(const int* __restrict__ rowptr, int* __restrict__ bsum) {
    __shared__ int red[256];
    const int t = threadIdx.x, b = blockIdx.x;
    const int base = b * 1024;
    int s = 0;
    for (int i = t; i < 1024; i += 256) {
        const int idx = base + i;
        s += (idx < NN) ? rowptr[idx] : 0;
    }
    red[t] = s;
    __syncthreads();
    for (int off = 128; off > 0; off >>= 1) {
        if (t < off) red[t] += red[t + off];
        __syncthreads();
    }
    if (t == 0) bsum[b] = red[0];
}

__global__ __launch_bounds__(128) void scan2_kernel(int* __restrict__ bsum) {
    __shared__ int s[128];
    const int t = threadIdx.x;
    const int v = (t < SCAN_B) ? bsum[t] : 0;
    s[t] = v;
    __syncthreads();
    for (int off = 1; off < 128; off <<= 1) {
        const int x = (t >= off) ? s[t - off] : 0;
        __syncthreads();
        s[t] += x;
        __syncthreads();
    }
    if (t < SCAN_B) bsum[t] = s[t] - v;  // exclusive
}

__global__ __launch_bounds__(256) void scan3_kernel(int* __restrict__ rowptr, const int* __restrict__ bsum,
                                                    float* __restrict__ deg) {
    __shared__ int red[256];
    const int t = threadIdx.x, b = blockIdx.x;
    const int i0 = b * 1024 + t * 4;
    int v[4];
#pragma unroll
    for (int j = 0; j < 4; ++j) v[j] = (i0 + j < NN) ? rowptr[i0 + j] : 0;
    const int ts = v[0] + v[1] + v[2] + v[3];
    red[t] = ts;
    __syncthreads();
    for (int off = 1; off < 256; off <<= 1) {
        const int x = (t >= off) ? red[t - off] : 0;
        __syncthreads();
        red[t] += x;
        __syncthreads();
    }
    int pre = bsum[b] + red[t] - ts;
#pragma unroll
    for (int j = 0; j < 4; ++j) {
        if (i0 + j < NN) {
            rowptr[i0 + j] = pre;
            deg[i0 + j] = (float)v[j];
            pre += v[j];
        }
    }
}

// ---- CSR build: fill. Uses rowptr as cursor; afterwards rowptr[n] == end offset of node n ----
__global__ __launch_bounds__(256) void fill_kernel(
    const int* __restrict__ adj, int* __restrict__ rowptr, int* __restrict__ csr) {
    const int e = blockIdx.x * 256 + threadIdx.x;
    if (e < NE) {
        const int2 st = ((const int2*)adj)[e];
        const int pos = atomicAdd(&rowptr[st.y], 1);
        csr[pos] = st.x;
    }
}

// ---- aggb[n] = bf16( sum over in-edges of fp8 hb8[src] ). 8 lanes x 8 bytes per node. ----
// aggb element index p holds feature (p&3)*16+(p>>2) — consumed by the permuted Wpk.
__global__ __launch_bounds__(256) void agg_kernel(
    const int* __restrict__ rowptr, const int* __restrict__ csr,
    const unsigned char* __restrict__ hb8, unsigned short* __restrict__ aggb) {
    const int t = threadIdx.x;
    const int node = blockIdx.x * 32 + (t >> 3);
    const int c = t & 7;
    const int start = node ? rowptr[node - 1] : 0;
    const int end = rowptr[node];
    float acc[8];
#pragma unroll
    for (int j = 0; j < 8; ++j) acc[j] = 0.f;
    int e = start;
    for (; e + 7 < end; e += 8) {
        int s[8];
        uint2 u[8];
#pragma unroll
        for (int q = 0; q < 8; ++q) s[q] = csr[e + q];
#pragma unroll
        for (int q = 0; q < 8; ++q) u[q] = *(const uint2*)(hb8 + (size_t)s[q] * 64 + c * 8);
#pragma unroll
        for (int q = 0; q < 8; ++q) {
            const f32x2 a0 = __builtin_amdgcn_cvt_pk_f32_fp8(u[q].x, false);
            const f32x2 a1 = __builtin_amdgcn_cvt_pk_f32_fp8(u[q].x, true);
            const f32x2 a2 = __builtin_amdgcn_cvt_pk_f32_fp8(u[q].y, false);
            const f32x2 a3 = __builtin_amdgcn_cvt_pk_f32_fp8(u[q].y, true);
            acc[0] += a0.x; acc[1] += a0.y; acc[2] += a1.x; acc[3] += a1.y;
            acc[4] += a2.x; acc[5] += a2.y; acc[6] += a3.x; acc[7] += a3.y;
        }
    }
    for (; e < end; ++e) {
        const uint2 u = *(const uint2*)(hb8 + (size_t)csr[e] * 64 + c * 8);
        const f32x2 a0 = __builtin_amdgcn_cvt_pk_f32_fp8(u.x, false);
        const f32x2 a1 = __builtin_amdgcn_cvt_pk_f32_fp8(u.x, true);
        const f32x2 a2 = __builtin_amdgcn_cvt_pk_f32_fp8(u.y, false);
        const f32x2 a3 = __builtin_amdgcn_cvt_pk_f32_fp8(u.y, true);
        acc[0] += a0.x; acc[1] += a0.y; acc[2] += a1.x; acc[3] += a1.y;
        acc[4] += a2.x; acc[5] += a2.y; acc[6] += a3.x; acc[7] += a3.y;
    }
    uint4 o;
    o.x = packb(acc[0], acc[1]);
    o.y = packb(acc[2], acc[3]);
    o.z = packb(acc[4], acc[5]);
    o.w = packb(acc[6], acc[7]);
    *(uint4*)(aggb + node * 64 + c * 8) = o;
}

// ---- MFMA GRU: 256 thr, 2 M-tiles/wave, bf16 state, in-place hb + fp8 mirror hb8 ----
__global__ __launch_bounds__(256) void gru_mfma_kernel(
    unsigned short* __restrict__ hb, unsigned char* __restrict__ hb8,
    const unsigned short* __restrict__ aggb, const float* __restrict__ deg,
    const unsigned short* __restrict__ Wpk, const float* __restrict__ bf,
    const float* __restrict__ bih, const float* __restrict__ bhh) {
    extern __shared__ unsigned short ldsW[];  // 64 frags x 64 lanes x 8 bf16 = 64 KB
    {
        const uint4* src = (const uint4*)Wpk;
        uint4* dst = (uint4*)ldsW;
        for (int i = threadIdx.x; i < 4096; i += 256) dst[i] = src[i];
    }
    __syncthreads();
    const int lane = threadIdx.x & 63;
    const int j0 = lane & 15, quad = lane >> 4;
    const int q8 = quad * 8;
    float cr[4], cz[4], cig[4], chg[4], vbfr[4], vbfz[4], vbfg[4];
#pragma unroll
    for (int c4 = 0; c4 < 4; ++c4) {
        const int col = c4 * 16 + j0;
        cr[c4] = bih[col] + bhh[col];
        cz[c4] = bih[64 + col] + bhh[64 + col];
        cig[c4] = bih[128 + col];
        chg[c4] = bhh[128 + col];
        vbfr[c4] = bf[col];
        vbfz[c4] = bf[64 + col];
        vbfg[c4] = bf[128 + col];
    }
    const short8* ldsW8 = (const short8*)ldsW;
    const int gw = blockIdx.x * 4 + (threadIdx.x >> 6);
    const int nw = gridDim.x * 4;

    auto epilogue = [&](const f32x4(&acc)[16], int nb) {
#pragma unroll
        for (int reg = 0; reg < 4; ++reg) {
            const int node = nb + reg;
            const float dg = deg[node];
            float hn[4];
#pragma unroll
            for (int c4 = 0; c4 < 4; ++c4) {
                const int col = c4 * 16 + j0;
                const float rv = sig1(acc[c4][reg] + cr[c4] + dg * vbfr[c4]);
                const float zv = sig1(acc[4 + c4][reg] + cz[c4] + dg * vbfz[c4]);
                const float gi = acc[8 + c4][reg] + cig[c4] + dg * vbfg[c4];
                const float gh = acc[12 + c4][reg] + chg[c4];
                const float nv = tanh1(fmaf(rv, gh, gi));
                const float hold = b2f(hb[node * 64 + col]);  // L1-hot (tile just read)
                hn[c4] = (1.f - zv) * nv + zv * hold;
                hb[node * 64 + col] = f2b(hn[c4]);
            }
            // fp8 mirror: word j0 of node's row = cols {j0, 16+j0, 32+j0, 48+j0}
            ((unsigned*)(hb8 + (size_t)node * 64))[j0] = pk8(hn[0], hn[1], hn[2], hn[3]);
        }
    };

    for (int t = gw; t < NN / 32; t += nw) {
        const int mbase = t * 32;
        const int node0 = mbase + j0, node1 = node0 + 16;
        short8 a[4], b[4];
        a[0] = *(const short8*)(aggb + node0 * 64 + q8);
        a[1] = *(const short8*)(aggb + node0 * 64 + 32 + q8);
        a[2] = *(const short8*)(hb + node0 * 64 + q8);
        a[3] = *(const short8*)(hb + node0 * 64 + 32 + q8);
        b[0] = *(const short8*)(aggb + node1 * 64 + q8);
        b[1] = *(const short8*)(aggb + node1 * 64 + 32 + q8);
        b[2] = *(const short8*)(hb + node1 * 64 + q8);
        b[3] = *(const short8*)(hb + node1 * 64 + 32 + q8);
        f32x4 acc0[16], acc1[16];
#pragma unroll
        for (int i = 0; i < 16; ++i) {
            acc0[i] = (f32x4){0.f, 0.f, 0.f, 0.f};
            acc1[i] = (f32x4){0.f, 0.f, 0.f, 0.f};
        }
#pragma unroll
        for (int nt = 0; nt < 16; ++nt) {
#pragma unroll
            for (int kk = 0; kk < 4; ++kk) {
                const short8 w = ldsW8[(nt * 4 + kk) * 64 + lane];
                acc0[nt] = __builtin_amdgcn_mfma_f32_16x16x32_bf16(a[kk], w, acc0[nt], 0, 0, 0);
                acc1[nt] = __builtin_amdgcn_mfma_f32_16x16x32_bf16(b[kk], w, acc1[nt], 0, 0, 0);
            }
        }
        epilogue(acc0, mbase + quad * 4);
        epilogue(acc1, mbase + 16 + quad * 4);
    }
}

// ---- X[b, g*64 + j] = f32(hb[prop[b]][j]) ----
__global__ __launch_bounds__(256) void gather_kernel(
    const int* __restrict__ prop, const unsigned short* __restrict__ hb, float* __restrict__ X, int g) {
    const int b = blockIdx.x * 4 + (threadIdx.x >> 6);
    const int j = threadIdx.x & 63;
    X[b * 128 + g * 64 + j] = b2f(hb[prop[b] * 64 + j]);
}

// ---- hidden = relu(X@W1+b1); z = hidden@W2+b2; out[b]=sigmoid(z); zbuf[b]=z ----
__global__ __launch_bounds__(256) void mlp_kernel(
    const float* __restrict__ X, const float* __restrict__ W1, const float* __restrict__ b1,
    const float* __restrict__ W2, const float* __restrict__ b2,
    float* __restrict__ out, float* __restrict__ zbuf) {
    const int b = blockIdx.x * 4 + (threadIdx.x >> 6);
    const int j = threadIdx.x & 63;
    const float* x = X + b * 128;
    float acc = b1[j];
#pragma unroll 4
    for (int k = 0; k < 128; ++k) acc = fmaf(x[k], W1[k * 64 + j], acc);
    float v = fmaxf(acc, 0.f) * W2[j];
#pragma unroll
    for (int off = 32; off > 0; off >>= 1) v += __shfl_down(v, off);
    if (j == 0) {
        const float z = v + b2[0];
        out[b] = 1.f / (1.f + expf(-z));
        zbuf[b] = z;
    }
}

// ---- loss = -mean(y*logsig(z) + (1-y)*logsig(-z)) -> out[BT] ----
__global__ __launch_bounds__(256) void loss_kernel(
    const float* __restrict__ zbuf, const int* __restrict__ labels, float* __restrict__ out) {
    __shared__ float red[256];
    const int t = threadIdx.x;
    float s = 0.f;
    for (int i = t; i < BT; i += 256) {
        const float z = zbuf[i];
        const float y = (float)labels[i];
        const float lsp = (z >= 0.f) ? -log1pf(expf(-z)) : (z - log1pf(expf(z)));
        const float lsn = lsp - z;
        s += y * lsp + (1.f - y) * lsn;
    }
    red[t] = s;
    __syncthreads();
    for (int off = 128; off > 0; off >>= 1) {
        if (t < off) red[t] += red[t + off];
        __syncthreads();
    }
    if (t == 0) out[BT] = -red[0] / (float)BT;
}

extern "C" void kernel_launch(void* const* d_in, const int* in_sizes, int n_in,
                              void* d_out, int out_size, void* d_ws, size_t ws_size,
                              hipStream_t stream) {
    char* ws = (char*)d_ws;
    unsigned short* hb = (unsigned short*)(ws);               // 12,800,000 B
    unsigned short* aggb = (unsigned short*)(ws + 12800000);  // 12,800,000 B
    unsigned char* hb8 = (unsigned char*)(ws + 25600000);     // 6,400,000 B
    float* deg = (float*)(ws + 32000000);                     // 400,000 B
    float* Wf = (float*)(ws + 32400000);                      // 98,304 B
    float* bf = (float*)(ws + 32498304);                      // 1,536 B
    int* rowptr = (int*)(ws + 32499840);                      // 400,000 B
    int* csr = (int*)(ws + 32899840);                         // 4,800,000 B
    int* bsum = (int*)(ws + 37699840);                        // 512 B
    float* X = (float*)(ws + 37700352);                       // 2,097,152 B
    float* zbuf = (float*)(ws + 39797504);                    // 16,384 B
    unsigned short* Wpk = (unsigned short*)(ws + 39813888);   // 131,072 B
    float* out = (float*)d_out;

    const float* emb_table = (const float*)d_in[7];
    const float* Wp = (const float*)d_in[8];
    const float* bp = (const float*)d_in[9];

    fusew_kernel<<<16, 256, 65536, stream>>>(
        (const float*)d_in[10], (const float*)d_in[12], (const float*)d_in[11],
        (const float*)d_in[16], (const float*)d_in[18], (const float*)d_in[17], Wf, bf);
    wpack_kernel<<<128, 64, 0, stream>>>(Wf, (const float*)d_in[13], (const float*)d_in[19], Wpk);

    for (int g = 0; g < 2; ++g) {
        const int* adjg = (const int*)d_in[2 + g];
        // CSR build for this graph
        hipMemsetAsync(rowptr, 0, (size_t)NN * 4, stream);
        hist_kernel<<<(NE + 255) / 256, 256, 0, stream>>>(adjg, rowptr);
        scan1_kernel<<<SCAN_B, 256, 0, stream>>>(rowptr, bsum);
        scan2_kernel<<<1, 128, 0, stream>>>(bsum);
        scan3_kernel<<<SCAN_B, 256, 0, stream>>>(rowptr, bsum, deg);
        fill_kernel<<<(NE + 255) / 256, 256, 0, stream>>>(adjg, rowptr, csr);

        embed_kernel<<<NN / 16, 256, 0, stream>>>((const int*)d_in[g], emb_table, Wp, bp, hb, hb8);
        for (int l = 0; l < 2; ++l) {
            const float* bih = (const float*)d_in[14 + 6 * l];
            const float* bhh = (const float*)d_in[15 + 6 * l];
            for (int ts = 0; ts < 3; ++ts) {
                agg_kernel<<<NN / 32, 256, 0, stream>>>(rowptr, csr, hb8, aggb);
                gru_mfma_kernel<<<512, 256, 65536, stream>>>(hb, hb8, aggb, deg, Wpk + l * 32768,
                                                             bf + l * 192, bih, bhh);
            }
        }
        gather_kernel<<<BT / 4, 256, 0, stream>>>((const int*)d_in[4 + g], hb, X, g);
    }
    mlp_kernel<<<BT / 4, 256, 0, stream>>>(X, (const float*)d_in[22], (const float*)d_in[23],
                                           (const float*)d_in[24], (const float*)d_in[25], out, zbuf);
    loss_kernel<<<1, 256, 0, stream>>>(zbuf, (const int*)d_in[6], out);
}

// Round 10
// 1223.196 us; speedup vs baseline: 1.7355x; 1.1316x over previous
//
#include <hip/hip_runtime.h>
#include <math.h>

#define NN 100000
#define NN2 200000
#define NE 1200000
#define EMBD 100
#define HD 64
#define BT 4096
#define SCAN_B 196  // 196 * 1024 >= NN2

typedef __attribute__((ext_vector_type(8))) short short8;  // 8 bf16 (4 VGPRs)
typedef __attribute__((ext_vector_type(4))) float f32x4;   // MFMA C/D
typedef __attribute__((ext_vector_type(2))) float f32x2;   // fp8 pk-cvt result

__device__ __forceinline__ float sig1(float x) { return 1.f / (1.f + __expf(-x)); }
__device__ __forceinline__ float tanh1(float x) {
    x = fminf(fmaxf(x, -15.f), 15.f);
    float e = __expf(2.f * x);
    return (e - 1.f) / (e + 1.f);
}
__device__ __forceinline__ unsigned short f2b(float f) {
    unsigned u = __float_as_uint(f);
    u += 0x7fffu + ((u >> 16) & 1u);
    return (unsigned short)(u >> 16);
}
__device__ __forceinline__ float b2f(unsigned short s) { return __uint_as_float(((unsigned)s) << 16); }
__device__ __forceinline__ float blo(unsigned u) { return __uint_as_float(u << 16); }
__device__ __forceinline__ float bhi(unsigned u) { return __uint_as_float(u & 0xffff0000u); }
__device__ __forceinline__ unsigned packb(float lo, float hi) {
    return (unsigned)f2b(lo) | ((unsigned)f2b(hi) << 16);
}
// fp8 e4m3 HW pack. hb8 row layout: byte p holds feature (p&3)*16 + (p>>2) [baked into wpack]
__device__ __forceinline__ unsigned pk8(float a, float b, float c, float d) {
    int w = 0;
    w = __builtin_amdgcn_cvt_pk_fp8_f32(a, b, w, false);
    w = __builtin_amdgcn_cvt_pk_fp8_f32(c, d, w, true);
    return (unsigned)w;
}

// ---- precompute Wf[l] = Wm[l] @ Wih[l] (64x192), bf[l] = bm[l] @ Wih[l] (192) ----
__global__ __launch_bounds__(256) void fusew_kernel(
    const float* __restrict__ Wm0, const float* __restrict__ Wih0, const float* __restrict__ bm0,
    const float* __restrict__ Wm1, const float* __restrict__ Wih1, const float* __restrict__ bm1,
    float* __restrict__ Wf, float* __restrict__ bf) {
    extern __shared__ float lds[];
    float* wm_s = lds;          // 4096
    float* wih_s = lds + 4096;  // 12288
    const int l = blockIdx.x >> 3, slice = blockIdx.x & 7;
    const float* Wm = l ? Wm1 : Wm0;
    const float* Wih = l ? Wih1 : Wih0;
    const float* bm = l ? bm1 : bm0;
    for (int i = threadIdx.x; i < 4096; i += 256) wm_s[i] = Wm[i];
    for (int i = threadIdx.x; i < 12288; i += 256) wih_s[i] = Wih[i];
    __syncthreads();
    float* Wfl = Wf + l * 12288;
    float* bfl = bf + l * 192;
    const int o0 = slice * 1536;
    for (int o = o0 + threadIdx.x; o < o0 + 1536; o += 256) {
        int r = o / 192, c = o % 192;
        float s = 0.f;
        for (int k = 0; k < 64; ++k) s = fmaf(wm_s[r * 64 + k], wih_s[k * 192 + c], s);
        Wfl[o] = s;
    }
    const int c0 = slice * 24;
    for (int c = c0 + threadIdx.x; c < c0 + 24; c += 256) {
        float s = 0.f;
        for (int k = 0; k < 64; ++k) s = fmaf(bm[k], wih_s[k * 192 + c], s);
        bfl[c] = s;
    }
}

// ---- pack W' (128x256) into MFMA B-fragment order, bf16.
// agg half (k<64) uses PERMUTED Wf rows matching the fp8 row layout.
__global__ __launch_bounds__(64) void wpack_kernel(
    const float* __restrict__ Wf, const float* __restrict__ Whh0, const float* __restrict__ Whh1,
    unsigned short* __restrict__ Wpk) {
    const int b = blockIdx.x;  // 0..127
    const int l = b >> 6, frag = b & 63;
    const int nt = frag >> 2, kk = frag & 3;
    const int lane = threadIdx.x;
    const int n = nt * 16 + (lane & 15);
    const int g = n >> 6, j = n & 63;
    const int k0 = kk * 32 + (lane >> 4) * 8;
    const float* wf = Wf + l * 12288;
    const float* whh = l ? Whh1 : Whh0;
    unsigned short o[8];
#pragma unroll
    for (int jj = 0; jj < 8; ++jj) {
        const int k = k0 + jj;
        float v = 0.f;
        if (k < 64) {
            const int kp = (k & 3) * 16 + (k >> 2);  // fp8-gather layout permutation
            if (g == 0) v = wf[kp * 192 + j];
            else if (g == 1) v = wf[kp * 192 + 64 + j];
            else if (g == 2) v = wf[kp * 192 + 128 + j];
        } else {
            const int k2 = k - 64;
            if (g == 0) v = whh[k2 * 192 + j];
            else if (g == 1) v = whh[k2 * 192 + 64 + j];
            else if (g == 3) v = whh[k2 * 192 + 128 + j];
        }
        o[jj] = f2b(v);
    }
    *(uint4*)(Wpk + ((size_t)(l * 64 + frag) * 64 + lane) * 8) = *(const uint4*)o;
}

// ---- hb[n] = bf16( emb_table[ind[n]] @ Wp + bp ), plus fp8 mirror hb8 ----
__global__ __launch_bounds__(256) void embed_kernel(
    const int* __restrict__ ind, const float* __restrict__ emb,
    const float* __restrict__ Wp, const float* __restrict__ bp,
    unsigned short* __restrict__ hb, unsigned char* __restrict__ hb8) {
    __shared__ float et[4][EMBD][4];  // [wave][k][node]
    const int w = threadIdx.x >> 6;
    const int l = threadIdx.x & 63;
    const int nodeBase = blockIdx.x * 16 + w * 4;
    for (int f = l; f < 100; f += 64) {
        const int n = f / 25, c = f % 25;
        const int idx = ind[nodeBase + n];
        const float4 v = *(const float4*)(emb + (size_t)idx * EMBD + c * 4);
        et[w][c * 4 + 0][n] = v.x;
        et[w][c * 4 + 1][n] = v.y;
        et[w][c * 4 + 2][n] = v.z;
        et[w][c * 4 + 3][n] = v.w;
    }
    __syncthreads();
    float acc[4];
    acc[0] = bp[l]; acc[1] = acc[0]; acc[2] = acc[0]; acc[3] = acc[0];
#pragma unroll 5
    for (int k = 0; k < EMBD; ++k) {
        const float wv = Wp[k * 64 + l];
        const float4 ev = *(const float4*)&et[w][k][0];
        acc[0] = fmaf(ev.x, wv, acc[0]);
        acc[1] = fmaf(ev.y, wv, acc[1]);
        acc[2] = fmaf(ev.z, wv, acc[2]);
        acc[3] = fmaf(ev.w, wv, acc[3]);
    }
#pragma unroll
    for (int n = 0; n < 4; ++n) {
        hb[(nodeBase + n) * 64 + l] = f2b(acc[n]);
        const float v0 = __shfl(acc[n], l & 15);
        const float v1 = __shfl(acc[n], (l & 15) + 16);
        const float v2 = __shfl(acc[n], (l & 15) + 32);
        const float v3 = __shfl(acc[n], (l & 15) + 48);
        if (l < 16) ((unsigned*)(hb8 + (size_t)(nodeBase + n) * 64))[l] = pk8(v0, v1, v2, v3);
    }
}

// ---- CSR build (combined node space, graph offset in `off`) ----
__global__ __launch_bounds__(256) void hist_kernel(const int* __restrict__ adj, int* __restrict__ rowptr,
                                                   int off) {
    const int e = blockIdx.x * 256 + threadIdx.x;
    if (e < NE) atomicAdd(&rowptr[adj[2 * e + 1] + off], 1);
}

__global__ __launch_bounds__(256) void scan1_kernel(const int* __restrict__ rowptr, int* __restrict__ bsum) {
    __shared__ int red[256];
    const int t = threadIdx.x, b = blockIdx.x;
    const int base = b * 1024;
    int s = 0;
    for (int i = t; i < 1024; i += 256) {
        const int idx = base + i;
        s += (idx < NN2) ? rowptr[idx] : 0;
    }
    red[t] = s;
    __syncthreads();
    for (int off = 128; off > 0; off >>= 1) {
        if (t < off) red[t] += red[t + off];
        __syncthreads();
    }
    if (t == 0) bsum[b] = red[0];
}

__global__ __launch_bounds__(256) void scan2_kernel(int* __restrict__ bsum) {
    __shared__ int s[256];
    const int t = threadIdx.x;
    const int v = (t < SCAN_B) ? bsum[t] : 0;
    s[t] = v;
    __syncthreads();
    for (int off = 1; off < 256; off <<= 1) {
        const int x = (t >= off) ? s[t - off] : 0;
        __syncthreads();
        s[t] += x;
        __syncthreads();
    }
    if (t < SCAN_B) bsum[t] = s[t] - v;  // exclusive
}

__global__ __launch_bounds__(256) void scan3_kernel(int* __restrict__ rowptr, const int* __restrict__ bsum,
                                                    float* __restrict__ deg) {
    __shared__ int red[256];
    const int t = threadIdx.x, b = blockIdx.x;
    const int i0 = b * 1024 + t * 4;
    int v[4];
#pragma unroll
    for (int j = 0; j < 4; ++j) v[j] = (i0 + j < NN2) ? rowptr[i0 + j] : 0;
    const int ts = v[0] + v[1] + v[2] + v[3];
    red[t] = ts;
    __syncthreads();
    for (int off = 1; off < 256; off <<= 1) {
        const int x = (t >= off) ? red[t - off] : 0;
        __syncthreads();
        red[t] += x;
        __syncthreads();
    }
    int pre = bsum[b] + red[t] - ts;
#pragma unroll
    for (int j = 0; j < 4; ++j) {
        if (i0 + j < NN2) {
            rowptr[i0 + j] = pre;
            deg[i0 + j] = (float)v[j];
            pre += v[j];
        }
    }
}

__global__ __launch_bounds__(256) void fill_kernel(
    const int* __restrict__ adj, int* __restrict__ rowptr, int* __restrict__ csr, int off) {
    const int e = blockIdx.x * 256 + threadIdx.x;
    if (e < NE) {
        const int2 st = ((const int2*)adj)[e];
        const int pos = atomicAdd(&rowptr[st.y + off], 1);
        csr[pos] = st.x + off;
    }
}

// ---- aggb[n] = bf16( sum over in-edges of fp8 hb8[src] ). 8 lanes x 8 bytes per node. ----
__global__ __launch_bounds__(256) void agg_kernel(
    const int* __restrict__ rowptr, const int* __restrict__ csr,
    const unsigned char* __restrict__ hb8, unsigned short* __restrict__ aggb) {
    const int t = threadIdx.x;
    const int node = blockIdx.x * 32 + (t >> 3);
    const int c = t & 7;
    const int start = node ? rowptr[node - 1] : 0;
    const int end = rowptr[node];
    float acc[8];
#pragma unroll
    for (int j = 0; j < 8; ++j) acc[j] = 0.f;
    int e = start;
    for (; e + 7 < end; e += 8) {
        int s[8];
        uint2 u[8];
#pragma unroll
        for (int q = 0; q < 8; ++q) s[q] = csr[e + q];
#pragma unroll
        for (int q = 0; q < 8; ++q) u[q] = *(const uint2*)(hb8 + (size_t)s[q] * 64 + c * 8);
#pragma unroll
        for (int q = 0; q < 8; ++q) {
            const f32x2 a0 = __builtin_amdgcn_cvt_pk_f32_fp8(u[q].x, false);
            const f32x2 a1 = __builtin_amdgcn_cvt_pk_f32_fp8(u[q].x, true);
            const f32x2 a2 = __builtin_amdgcn_cvt_pk_f32_fp8(u[q].y, false);
            const f32x2 a3 = __builtin_amdgcn_cvt_pk_f32_fp8(u[q].y, true);
            acc[0] += a0.x; acc[1] += a0.y; acc[2] += a1.x; acc[3] += a1.y;
            acc[4] += a2.x; acc[5] += a2.y; acc[6] += a3.x; acc[7] += a3.y;
        }
    }
    for (; e < end; ++e) {
        const uint2 u = *(const uint2*)(hb8 + (size_t)csr[e] * 64 + c * 8);
        const f32x2 a0 = __builtin_amdgcn_cvt_pk_f32_fp8(u.x, false);
        const f32x2 a1 = __builtin_amdgcn_cvt_pk_f32_fp8(u.x, true);
        const f32x2 a2 = __builtin_amdgcn_cvt_pk_f32_fp8(u.y, false);
        const f32x2 a3 = __builtin_amdgcn_cvt_pk_f32_fp8(u.y, true);
        acc[0] += a0.x; acc[1] += a0.y; acc[2] += a1.x; acc[3] += a1.y;
        acc[4] += a2.x; acc[5] += a2.y; acc[6] += a3.x; acc[7] += a3.y;
    }
    uint4 o;
    o.x = packb(acc[0], acc[1]);
    o.y = packb(acc[2], acc[3]);
    o.z = packb(acc[4], acc[5]);
    o.w = packb(acc[6], acc[7]);
    *(uint4*)(aggb + node * 64 + c * 8) = o;
}

// ---- MFMA GRU: 256 thr, 2 M-tiles/wave, bf16 state, in-place hb + fp8 mirror hb8 ----
__global__ __launch_bounds__(256) void gru_mfma_kernel(
    unsigned short* __restrict__ hb, unsigned char* __restrict__ hb8,
    const unsigned short* __restrict__ aggb, const float* __restrict__ deg,
    const unsigned short* __restrict__ Wpk, const float* __restrict__ bf,
    const float* __restrict__ bih, const float* __restrict__ bhh) {
    extern __shared__ unsigned short ldsW[];  // 64 frags x 64 lanes x 8 bf16 = 64 KB
    {
        const uint4* src = (const uint4*)Wpk;
        uint4* dst = (uint4*)ldsW;
        for (int i = threadIdx.x; i < 4096; i += 256) dst[i] = src[i];
    }
    __syncthreads();
    const int lane = threadIdx.x & 63;
    const int j0 = lane & 15, quad = lane >> 4;
    const int q8 = quad * 8;
    float cr[4], cz[4], cig[4], chg[4], vbfr[4], vbfz[4], vbfg[4];
#pragma unroll
    for (int c4 = 0; c4 < 4; ++c4) {
        const int col = c4 * 16 + j0;
        cr[c4] = bih[col] + bhh[col];
        cz[c4] = bih[64 + col] + bhh[64 + col];
        cig[c4] = bih[128 + col];
        chg[c4] = bhh[128 + col];
        vbfr[c4] = bf[col];
        vbfz[c4] = bf[64 + col];
        vbfg[c4] = bf[128 + col];
    }
    const short8* ldsW8 = (const short8*)ldsW;
    const int gw = blockIdx.x * 4 + (threadIdx.x >> 6);
    const int nw = gridDim.x * 4;

    auto epilogue = [&](const f32x4(&acc)[16], int nb) {
#pragma unroll
        for (int reg = 0; reg < 4; ++reg) {
            const int node = nb + reg;
            const float dg = deg[node];
            float hn[4];
#pragma unroll
            for (int c4 = 0; c4 < 4; ++c4) {
                const int col = c4 * 16 + j0;
                const float rv = sig1(acc[c4][reg] + cr[c4] + dg * vbfr[c4]);
                const float zv = sig1(acc[4 + c4][reg] + cz[c4] + dg * vbfz[c4]);
                const float gi = acc[8 + c4][reg] + cig[c4] + dg * vbfg[c4];
                const float gh = acc[12 + c4][reg] + chg[c4];
                const float nv = tanh1(fmaf(rv, gh, gi));
                const float hold = b2f(hb[node * 64 + col]);  // L1-hot (tile just read)
                hn[c4] = (1.f - zv) * nv + zv * hold;
                hb[node * 64 + col] = f2b(hn[c4]);
            }
            ((unsigned*)(hb8 + (size_t)node * 64))[j0] = pk8(hn[0], hn[1], hn[2], hn[3]);
        }
    };

    for (int t = gw; t < NN2 / 32; t += nw) {
        const int mbase = t * 32;
        const int node0 = mbase + j0, node1 = node0 + 16;
        short8 a[4], b[4];
        a[0] = *(const short8*)(aggb + node0 * 64 + q8);
        a[1] = *(const short8*)(aggb + node0 * 64 + 32 + q8);
        a[2] = *(const short8*)(hb + node0 * 64 + q8);
        a[3] = *(const short8*)(hb + node0 * 64 + 32 + q8);
        b[0] = *(const short8*)(aggb + node1 * 64 + q8);
        b[1] = *(const short8*)(aggb + node1 * 64 + 32 + q8);
        b[2] = *(const short8*)(hb + node1 * 64 + q8);
        b[3] = *(const short8*)(hb + node1 * 64 + 32 + q8);
        f32x4 acc0[16], acc1[16];
#pragma unroll
        for (int i = 0; i < 16; ++i) {
            acc0[i] = (f32x4){0.f, 0.f, 0.f, 0.f};
            acc1[i] = (f32x4){0.f, 0.f, 0.f, 0.f};
        }
#pragma unroll
        for (int nt = 0; nt < 16; ++nt) {
#pragma unroll
            for (int kk = 0; kk < 4; ++kk) {
                const short8 w = ldsW8[(nt * 4 + kk) * 64 + lane];
                acc0[nt] = __builtin_amdgcn_mfma_f32_16x16x32_bf16(a[kk], w, acc0[nt], 0, 0, 0);
                acc1[nt] = __builtin_amdgcn_mfma_f32_16x16x32_bf16(b[kk], w, acc1[nt], 0, 0, 0);
            }
        }
        epilogue(acc0, mbase + quad * 4);
        epilogue(acc1, mbase + 16 + quad * 4);
    }
}

// ---- X[b, g*64 + j] = f32(hb[prop[b]][j]) ----
__global__ __launch_bounds__(256) void gather_kernel(
    const int* __restrict__ prop, const unsigned short* __restrict__ hb, float* __restrict__ X, int g) {
    const int b = blockIdx.x * 4 + (threadIdx.x >> 6);
    const int j = threadIdx.x & 63;
    X[b * 128 + g * 64 + j] = b2f(hb[prop[b] * 64 + j]);
}

// ---- hidden = relu(X@W1+b1); z = hidden@W2+b2; out[b]=sigmoid(z); zbuf[b]=z ----
__global__ __launch_bounds__(256) void mlp_kernel(
    const float* __restrict__ X, const float* __restrict__ W1, const float* __restrict__ b1,
    const float* __restrict__ W2, const float* __restrict__ b2,
    float* __restrict__ out, float* __restrict__ zbuf) {
    const int b = blockIdx.x * 4 + (threadIdx.x >> 6);
    const int j = threadIdx.x & 63;
    const float* x = X + b * 128;
    float acc = b1[j];
#pragma unroll 4
    for (int k = 0; k < 128; ++k) acc = fmaf(x[k], W1[k * 64 + j], acc);
    float v = fmaxf(acc, 0.f) * W2[j];
#pragma unroll
    for (int off = 32; off > 0; off >>= 1) v += __shfl_down(v, off);
    if (j == 0) {
        const float z = v + b2[0];
        out[b] = 1.f / (1.f + expf(-z));
        zbuf[b] = z;
    }
}

// ---- loss = -mean(y*logsig(z) + (1-y)*logsig(-z)) -> out[BT] ----
__global__ __launch_bounds__(256) void loss_kernel(
    const float* __restrict__ zbuf, const int* __restrict__ labels, float* __restrict__ out) {
    __shared__ float red[256];
    const int t = threadIdx.x;
    float s = 0.f;
    for (int i = t; i < BT; i += 256) {
        const float z = zbuf[i];
        const float y = (float)labels[i];
        const float lsp = (z >= 0.f) ? -log1pf(expf(-z)) : (z - log1pf(expf(z)));
        const float lsn = lsp - z;
        s += y * lsp + (1.f - y) * lsn;
    }
    red[t] = s;
    __syncthreads();
    for (int off = 128; off > 0; off >>= 1) {
        if (t < off) red[t] += red[t + off];
        __syncthreads();
    }
    if (t == 0) out[BT] = -red[0] / (float)BT;
}

extern "C" void kernel_launch(void* const* d_in, const int* in_sizes, int n_in,
                              void* d_out, int out_size, void* d_ws, size_t ws_size,
                              hipStream_t stream) {
    char* ws = (char*)d_ws;
    unsigned short* hb = (unsigned short*)(ws);               // 25,600,000 B  (NN2 rows)
    unsigned short* aggb = (unsigned short*)(ws + 25600000);  // 25,600,000 B
    unsigned char* hb8 = (unsigned char*)(ws + 51200000);     // 12,800,000 B
    float* deg = (float*)(ws + 64000000);                     // 800,000 B
    float* Wf = (float*)(ws + 64800000);                      // 98,304 B
    float* bf = (float*)(ws + 64898304);                      // 1,536 B
    int* rowptr = (int*)(ws + 64899840);                      // 800,000 B
    int* csr = (int*)(ws + 65699840);                         // 9,600,000 B
    int* bsum = (int*)(ws + 75299840);                        // 1,024 B
    unsigned short* Wpk = (unsigned short*)(ws + 75300864);   // 131,072 B
    // X/zbuf alias aggb: aggb is dead after the last gru; gathers run after.
    float* X = (float*)(ws + 25600000);
    float* zbuf = (float*)(ws + 25600000 + 2097152);
    float* out = (float*)d_out;

    const float* emb_table = (const float*)d_in[7];
    const float* Wp = (const float*)d_in[8];
    const float* bp = (const float*)d_in[9];

    fusew_kernel<<<16, 256, 65536, stream>>>(
        (const float*)d_in[10], (const float*)d_in[12], (const float*)d_in[11],
        (const float*)d_in[16], (const float*)d_in[18], (const float*)d_in[17], Wf, bf);
    wpack_kernel<<<128, 64, 0, stream>>>(Wf, (const float*)d_in[13], (const float*)d_in[19], Wpk);

    // ---- combined CSR build over both graphs (graph 1 offset by +NN) ----
    hipMemsetAsync(rowptr, 0, (size_t)NN2 * 4, stream);
    hist_kernel<<<(NE + 255) / 256, 256, 0, stream>>>((const int*)d_in[2], rowptr, 0);
    hist_kernel<<<(NE + 255) / 256, 256, 0, stream>>>((const int*)d_in[3], rowptr, NN);
    scan1_kernel<<<SCAN_B, 256, 0, stream>>>(rowptr, bsum);
    scan2_kernel<<<1, 256, 0, stream>>>(bsum);
    scan3_kernel<<<SCAN_B, 256, 0, stream>>>(rowptr, bsum, deg);
    fill_kernel<<<(NE + 255) / 256, 256, 0, stream>>>((const int*)d_in[2], rowptr, csr, 0);
    fill_kernel<<<(NE + 255) / 256, 256, 0, stream>>>((const int*)d_in[3], rowptr, csr, NN);

    // ---- embeddings for both graphs ----
    embed_kernel<<<NN / 16, 256, 0, stream>>>((const int*)d_in[0], emb_table, Wp, bp, hb, hb8);
    embed_kernel<<<NN / 16, 256, 0, stream>>>((const int*)d_in[1], emb_table, Wp, bp,
                                              hb + (size_t)NN * 64, hb8 + (size_t)NN * 64);

    // ---- batched GGNN chain: 12 dispatches over 200k nodes ----
    for (int l = 0; l < 2; ++l) {
        const float* bih = (const float*)d_in[14 + 6 * l];
        const float* bhh = (const float*)d_in[15 + 6 * l];
        for (int ts = 0; ts < 3; ++ts) {
            agg_kernel<<<NN2 / 32, 256, 0, stream>>>(rowptr, csr, hb8, aggb);
            gru_mfma_kernel<<<512, 256, 65536, stream>>>(hb, hb8, aggb, deg, Wpk + l * 32768,
                                                         bf + l * 192, bih, bhh);
        }
    }

    gather_kernel<<<BT / 4, 256, 0, stream>>>((const int*)d_in[4], hb, X, 0);
    gather_kernel<<<BT / 4, 256, 0, stream>>>((const int*)d_in[5], hb + (size_t)NN * 64, X, 1);
    mlp_kernel<<<BT / 4, 256, 0, stream>>>(X, (const float*)d_in[22], (const float*)d_in[23],
                                           (const float*)d_in[24], (const float*)d_in[25], out, zbuf);
    loss_kernel<<<1, 256, 0, stream>>>(zbuf, (const int*)d_in[6], out);
}